// Round 7
// baseline (741.151 us; speedup 1.0000x reference)
//
#include <hip/hip_runtime.h>

#define NB    2
#define NCAM  6
#define FD    256
#define KK    1680
#define DIMN  128
#define NHEAD 4
#define DHD   32
#define QQ    2500
#define SCALE 0.17677669529663687f

typedef short bf8 __attribute__((ext_vector_type(8)));
typedef float f4  __attribute__((ext_vector_type(4)));

__device__ __forceinline__ unsigned short f2bf(float f) {
  unsigned int u = __float_as_uint(f);
  unsigned int r = (u + 0x7fffu + ((u >> 16) & 1u)) >> 16;
  return (unsigned short)r;
}

// ---------- helpers ----------
__device__ __forceinline__ float blk_sum128(float v, float* red) {
  #pragma unroll
  for (int o = 32; o > 0; o >>= 1) v += __shfl_down(v, o);
  int t = threadIdx.x;
  if ((t & 63) == 0) red[t >> 6] = v;
  __syncthreads();
  float r = red[0] + red[1];
  __syncthreads();
  return r;
}

// ---------- K1: camera-center embedding ----------
__global__ void k_cembed(const float* __restrict__ W_cam, const float* __restrict__ E_inv,
                         float* __restrict__ ce) {
  int bn = blockIdx.x;
  int d  = threadIdx.x;
  const float* e = E_inv + bn * 16;
  float s = 0.f;
  #pragma unroll
  for (int c = 0; c < 4; ++c) s += W_cam[d * 4 + c] * e[c * 4 + 3];
  ce[bn * 128 + d] = s;
}

// ---------- K2: per-pixel ray embedding (normalized) -> key buffer ----------
__global__ void k_img(const float* __restrict__ I_inv, const float* __restrict__ E_inv,
                      const float* __restrict__ plane, const float* __restrict__ W_img,
                      const float* __restrict__ ce, float* __restrict__ key) {
  __shared__ float red[2];
  int p  = blockIdx.x;
  int bn = blockIdx.y;
  int d  = threadIdx.x;
  const float* Ii = I_inv + bn * 9;
  const float* Ei = E_inv + bn * 16;
  float pl0 = plane[p], pl1 = plane[KK + p], pl2 = plane[2 * KK + p];
  float c0 = Ii[0]*pl0 + Ii[1]*pl1 + Ii[2]*pl2;
  float c1 = Ii[3]*pl0 + Ii[4]*pl1 + Ii[5]*pl2;
  float c2 = Ii[6]*pl0 + Ii[7]*pl1 + Ii[8]*pl2;
  float d0 = Ei[0]*c0 + Ei[1]*c1 + Ei[2]*c2  + Ei[3];
  float d1 = Ei[4]*c0 + Ei[5]*c1 + Ei[6]*c2  + Ei[7];
  float d2 = Ei[8]*c0 + Ei[9]*c1 + Ei[10]*c2 + Ei[11];
  float d3 = Ei[12]*c0 + Ei[13]*c1 + Ei[14]*c2 + Ei[15];
  float v = W_img[d*4]*d0 + W_img[d*4+1]*d1 + W_img[d*4+2]*d2 + W_img[d*4+3]*d3
            - ce[bn * 128 + d];
  float ss = blk_sum128(v * v, red);
  float inv = 1.f / (sqrtf(ss) + 1e-7f);
  key[((size_t)bn * KK + p) * DIMN + d] = v * inv;
}

// ---------- K3: BEV positional embedding + x -> query buffer ----------
__global__ void k_query(const float* __restrict__ bev_grid, const float* __restrict__ W_bev,
                        const float* __restrict__ b_bev, const float* __restrict__ ce,
                        const float* __restrict__ x, float* __restrict__ query) {
  __shared__ float red[2];
  int q  = blockIdx.x;
  int bn = blockIdx.y;
  int b  = bn / NCAM;
  int d  = threadIdx.x;
  float g0 = bev_grid[q], g1 = bev_grid[QQ + q];
  float v = W_bev[d * 2] * g0 + W_bev[d * 2 + 1] * g1 + b_bev[d] - ce[bn * 128 + d];
  float ss = blk_sum128(v * v, red);
  float inv = 1.f / (sqrtf(ss) + 1e-7f);
  query[((size_t)bn * QQ + q) * DIMN + d] = v * inv + x[(size_t)(b * DIMN + d) * QQ + q];
}

// ---------- K4: BN+ReLU + dual 1x1 conv on feature; key += fproj, val = flin ----------
#define TP 16
__global__ void k_featconv(const float* __restrict__ feat,
                           const float* __restrict__ g1c, const float* __restrict__ b1c,
                           const float* __restrict__ m1c, const float* __restrict__ v1c,
                           const float* __restrict__ g2c, const float* __restrict__ b2c,
                           const float* __restrict__ m2c, const float* __restrict__ v2c,
                           const float* __restrict__ Wfp, const float* __restrict__ Wfl,
                           float* __restrict__ key, float* __restrict__ val) {
  __shared__ float sc1[FD], sh1[FD], sc2[FD], sh2[FD];
  __shared__ float t1[FD * (TP + 1)];
  __shared__ float t2[FD * (TP + 1)];
  int tile = blockIdx.x;
  int bn   = blockIdx.y;
  int t    = threadIdx.x;
  int p0   = tile * TP;
  {
    int c = t;
    float s1 = g1c[c] * rsqrtf(v1c[c] + 1e-5f);
    sc1[c] = s1; sh1[c] = b1c[c] - m1c[c] * s1;
    float s2 = g2c[c] * rsqrtf(v2c[c] + 1e-5f);
    sc2[c] = s2; sh2[c] = b2c[c] - m2c[c] * s2;
  }
  __syncthreads();
  const float* fb = feat + (size_t)bn * FD * KK + p0;
  int pp = t & 15, crow = t >> 4;
  #pragma unroll
  for (int i = 0; i < 16; ++i) {
    int c = i * 16 + crow;
    float raw = fb[(size_t)c * KK + pp];
    t1[c * (TP + 1) + pp] = fmaxf(raw * sc1[c] + sh1[c], 0.f);
    t2[c * (TP + 1) + pp] = fmaxf(raw * sc2[c] + sh2[c], 0.f);
  }
  __syncthreads();
  int dd = t & 127;
  const float4* W4 = (const float4*)((t < 128) ? Wfp : Wfl) + dd * 64;
  const float* tl = (t < 128) ? t1 : t2;
  float acc[TP];
  #pragma unroll
  for (int p = 0; p < TP; ++p) acc[p] = 0.f;
  for (int c4 = 0; c4 < 64; ++c4) {
    float4 w = W4[c4];
    const float* r0 = &tl[(c4 * 4 + 0) * (TP + 1)];
    const float* r1 = &tl[(c4 * 4 + 1) * (TP + 1)];
    const float* r2 = &tl[(c4 * 4 + 2) * (TP + 1)];
    const float* r3 = &tl[(c4 * 4 + 3) * (TP + 1)];
    #pragma unroll
    for (int p = 0; p < TP; ++p)
      acc[p] += w.x * r0[p] + w.y * r1[p] + w.z * r2[p] + w.w * r3[p];
  }
  __syncthreads();
  {
    float* dst = (t < 128) ? t1 : t2;
    #pragma unroll
    for (int p = 0; p < TP; ++p) dst[dd * (TP + 1) + p] = acc[p];
  }
  __syncthreads();
  #pragma unroll
  for (int i = 0; i < 16; ++i) {
    int e   = i * 256 + t;
    int ddo = e & 127, po = (e >> 7) & 15, wh = e >> 11;
    size_t addr = ((size_t)bn * KK + p0 + po) * DIMN + ddo;
    float vv = (wh ? t2 : t1)[ddo * (TP + 1) + po];
    if (wh) val[addr] = vv;
    else    key[addr] += vv;
  }
}

// ---------- K5: LayerNorm + 128x128 projection -> bf16 (MODE 0 row-major, MODE 1 V-transposed) ----------
#define ROWS 8
template<int MODE>
__global__ void k_lnproj_bf(const float* __restrict__ in, const float* __restrict__ lng,
                            const float* __restrict__ lnb, const float* __restrict__ W,
                            const float* __restrict__ bias, unsigned short* __restrict__ out,
                            float scale) {
  __shared__ float red[2];
  __shared__ float ln[ROWS][DIMN];
  __shared__ float stats[ROWS][2];
  size_t r0 = (size_t)blockIdx.x * ROWS;
  int t = threadIdx.x;
  float g = lng[t], bb = lnb[t];
  float xv[ROWS];
  #pragma unroll
  for (int r = 0; r < ROWS; ++r) xv[r] = in[(r0 + r) * DIMN + t];
  #pragma unroll
  for (int r = 0; r < ROWS; ++r) {
    float s  = blk_sum128(xv[r], red);
    float s2 = blk_sum128(xv[r] * xv[r], red);
    if (t == 0) { stats[r][0] = s * (1.f / 128.f); stats[r][1] = s2 * (1.f / 128.f); }
  }
  __syncthreads();
  #pragma unroll
  for (int r = 0; r < ROWS; ++r) {
    float mu  = stats[r][0];
    float var = fmaxf(stats[r][1] - mu * mu, 0.f);
    float rin = rsqrtf(var + 1e-5f);
    ln[r][t] = (xv[r] - mu) * rin * g + bb;
  }
  __syncthreads();
  float acc[ROWS];
  float bv = bias[t];
  #pragma unroll
  for (int r = 0; r < ROWS; ++r) acc[r] = bv;
  const float4* W4 = (const float4*)W + t * 32;
  for (int j4 = 0; j4 < 32; ++j4) {
    float4 w = W4[j4];
    #pragma unroll
    for (int r = 0; r < ROWS; ++r)
      acc[r] += w.x * ln[r][j4*4] + w.y * ln[r][j4*4+1] + w.z * ln[r][j4*4+2] + w.w * ln[r][j4*4+3];
  }
  if (MODE == 0) {
    #pragma unroll
    for (int r = 0; r < ROWS; ++r) out[(r0 + r) * DIMN + t] = f2bf(acc[r] * scale);
  } else {
    // V transposed: out[((bn*4+m)*32+d)*1680 + k], 8 consecutive k -> one 16B store
    int bn = (int)(r0 / KK), k0 = (int)(r0 % KK);
    int m = t >> 5, d = t & 31;
    unsigned int u0 = (unsigned int)f2bf(acc[0]) | ((unsigned int)f2bf(acc[1]) << 16);
    unsigned int u1 = (unsigned int)f2bf(acc[2]) | ((unsigned int)f2bf(acc[3]) << 16);
    unsigned int u2 = (unsigned int)f2bf(acc[4]) | ((unsigned int)f2bf(acc[5]) << 16);
    unsigned int u3 = (unsigned int)f2bf(acc[6]) | ((unsigned int)f2bf(acc[7]) << 16);
    uint4 pk = make_uint4(u0, u1, u2, u3);
    *(uint4*)&out[((size_t)((bn * 4 + m) * 32 + d)) * KK + k0] = pk;
  }
}

// ---------- K6: MFMA flash attention, 8-way split-K, two-pass softmax ----------
// Pass 1: QK^T only, per-lane running max (no cross-lane work), one shuffle tree at end.
// Pass 2: fixed-max softmax p=exp(s-m), per-lane partial l, P->LDS->PV MFMA.
// Cross-wave merge handles combining the 8 per-wave (m,l,o) partials.
#define AW 8
#define NCHUNK 53   // ceil(1680/32); chunk 52 has 16 keys
__global__ __launch_bounds__(512)
void k_attn_mfma(const unsigned short* __restrict__ qhB, const unsigned short* __restrict__ khB,
                 const unsigned short* __restrict__ vhB, float* __restrict__ aout) {
  __shared__ unsigned short pls[AW][16 * 40];   // per-wave P transpose buffer
  __shared__ float lds_o[AW][16][32];           // unnormalized o partials
  __shared__ float lds_m[AW][16], lds_l[AW][16];
  int qt = blockIdx.x, m = blockIdx.y, b = blockIdx.z;
  int t = threadIdx.x;
  int w = t >> 6, l = t & 63;
  int c = l & 15, g = l >> 4;
  int q0 = qt * 16;

  bf8 qf[NCAM];
  #pragma unroll
  for (int n = 0; n < NCAM; ++n) {
    int q = q0 + c;
    if (q < QQ)
      qf[n] = *(const bf8*)&qhB[((size_t)(b * NCAM + n) * QQ + q) * DIMN + m * DHD + g * 8];
    else
      qf[n] = (bf8)0;
  }
  const f4 z4 = {0.f, 0.f, 0.f, 0.f};

  // ---- pass 1: per-lane max over this wave's chunk subset ----
  float mx[4];
  #pragma unroll
  for (int i = 0; i < 4; ++i) mx[i] = -1e30f;
  for (int n = 0; n < NCAM; ++n) {
    const unsigned short* kb = khB + (size_t)(b * NCAM + n) * KK * DIMN + m * DHD;
    bf8 qa = qf[n];
    for (int j = w; j < NCHUNK; j += AW) {
      int k0 = j * 32;
      bf8 kf0 = *(const bf8*)&kb[(size_t)(k0 + c) * DIMN + g * 8];
      f4 s0 = __builtin_amdgcn_mfma_f32_16x16x32_bf16(qa, kf0, z4, 0, 0, 0);
      if (j != NCHUNK - 1) {
        bf8 kf1 = *(const bf8*)&kb[(size_t)(k0 + 16 + c) * DIMN + g * 8];
        f4 s1 = __builtin_amdgcn_mfma_f32_16x16x32_bf16(qa, kf1, z4, 0, 0, 0);
        #pragma unroll
        for (int i = 0; i < 4; ++i) mx[i] = fmaxf(mx[i], fmaxf(s0[i], s1[i]));
      } else {
        #pragma unroll
        for (int i = 0; i < 4; ++i) mx[i] = fmaxf(mx[i], s0[i]);
      }
    }
  }
  // one shuffle tree per row: reduce max over the 16 lanes of the group
  #pragma unroll
  for (int i = 0; i < 4; ++i) {
    #pragma unroll
    for (int msk = 1; msk < 16; msk <<= 1) mx[i] = fmaxf(mx[i], __shfl_xor(mx[i], msk, 16));
  }

  // ---- pass 2: fixed-max softmax + PV ----
  f4 o0 = {0.f, 0.f, 0.f, 0.f}, o1 = {0.f, 0.f, 0.f, 0.f};
  float lp[4];
  #pragma unroll
  for (int i = 0; i < 4; ++i) lp[i] = 0.f;
  for (int n = 0; n < NCAM; ++n) {
    const unsigned short* kb = khB + (size_t)(b * NCAM + n) * KK * DIMN + m * DHD;
    const unsigned short* vb = vhB + (size_t)((b * NCAM + n) * NHEAD + m) * DHD * KK;
    bf8 qa = qf[n];
    for (int j = w; j < NCHUNK; j += AW) {
      int k0 = j * 32;
      bool tail = (j == NCHUNK - 1);
      bf8 kf0 = *(const bf8*)&kb[(size_t)(k0 + c) * DIMN + g * 8];
      bf8 vf0 = *(const bf8*)&vb[(size_t)c * KK + k0 + g * 8];
      bf8 vf1 = *(const bf8*)&vb[(size_t)(16 + c) * KK + k0 + g * 8];
      f4 s0 = __builtin_amdgcn_mfma_f32_16x16x32_bf16(qa, kf0, z4, 0, 0, 0);
      f4 s1;
      if (!tail) {
        bf8 kf1 = *(const bf8*)&kb[(size_t)(k0 + 16 + c) * DIMN + g * 8];
        s1 = __builtin_amdgcn_mfma_f32_16x16x32_bf16(qa, kf1, z4, 0, 0, 0);
      } else {
        s1 = (f4){-1e30f, -1e30f, -1e30f, -1e30f};
      }
      #pragma unroll
      for (int i = 0; i < 4; ++i) {
        float p0 = __expf(s0[i] - mx[i]);
        float p1 = __expf(s1[i] - mx[i]);   // tail: exp(-inf) = 0
        lp[i] += p0 + p1;
        pls[w][(4 * g + i) * 40 + c]      = f2bf(p0);
        pls[w][(4 * g + i) * 40 + 16 + c] = f2bf(p1);
      }
      bf8 pa = *(const bf8*)&pls[w][c * 40 + g * 8];
      o0 = __builtin_amdgcn_mfma_f32_16x16x32_bf16(pa, vf0, o0, 0, 0, 0);
      o1 = __builtin_amdgcn_mfma_f32_16x16x32_bf16(pa, vf1, o1, 0, 0, 0);
    }
  }
  // one sum tree per row
  #pragma unroll
  for (int i = 0; i < 4; ++i) {
    #pragma unroll
    for (int msk = 1; msk < 16; msk <<= 1) lp[i] += __shfl_xor(lp[i], msk, 16);
  }
  // dump per-wave partials (unnormalized)
  #pragma unroll
  for (int i = 0; i < 4; ++i) {
    int qr = 4 * g + i;
    if (c == 0) { lds_m[w][qr] = mx[i]; lds_l[w][qr] = lp[i]; }
    lds_o[w][qr][c]      = o0[i];
    lds_o[w][qr][16 + c] = o1[i];
  }
  __syncthreads();
  // merge: 512 threads = 16 q x 32 d
  {
    int q = t >> 5, d = t & 31;
    float mg = -1e30f;
    #pragma unroll
    for (int ww = 0; ww < AW; ++ww) mg = fmaxf(mg, lds_m[ww][q]);
    float lg = 0.f, og = 0.f;
    #pragma unroll
    for (int ww = 0; ww < AW; ++ww) {
      float sc = __expf(lds_m[ww][q] - mg);
      lg += lds_l[ww][q] * sc;
      og += lds_o[ww][q][d] * sc;
    }
    int qq = q0 + q;
    if (qq < QQ)
      aout[((size_t)b * QQ + qq) * DIMN + m * DHD + d] = og / lg;
  }
}

// ---------- K7: tiled epilogue: 16 q / block, 256 threads ----------
#define EQ 16
#define EPAD 4
__global__ __launch_bounds__(256)
void k_epi2(const float* __restrict__ a, const float* __restrict__ x,
            const float* __restrict__ Wproj, const float* __restrict__ bproj,
            const float* __restrict__ preg, const float* __restrict__ preb,
            const float* __restrict__ W1, const float* __restrict__ b1,
            const float* __restrict__ W2, const float* __restrict__ b2,
            const float* __restrict__ postg, const float* __restrict__ postb,
            float* __restrict__ out) {
  __shared__ float sa[EQ][DIMN + EPAD];    // a tile, later final-output transpose buffer
  __shared__ float sx[EQ][DIMN + EPAD];    // x tile, later reduction scratch
  __shared__ float sln[EQ][DIMN + EPAD];   // preLN result
  __shared__ float sh[EQ][2 * DIMN];       // MLP hidden
  __shared__ float stats[EQ][2];
  int q0 = blockIdx.x * EQ;
  int b  = blockIdx.y;
  int t  = threadIdx.x;
  int d  = t & 127, rg = t >> 7;

  #pragma unroll
  for (int i = 0; i < 8; ++i) {
    int e = i * 256 + t;
    int q = e >> 7, dd = e & 127;
    int qq = q0 + q;
    sa[q][dd] = (qq < QQ) ? a[((size_t)b * QQ + qq) * DIMN + dd] : 0.f;
  }
  #pragma unroll
  for (int i = 0; i < 8; ++i) {
    int e = i * 256 + t;
    int dd = e >> 4, qi = e & 15;
    int qq = q0 + qi;
    sx[qi][dd] = (qq < QQ) ? x[((size_t)b * DIMN + dd) * QQ + qq] : 0.f;
  }
  __syncthreads();

  float z[8];
  {
    const float4* Wp = (const float4*)Wproj + d * 32;
    float bp = bproj[d];
    #pragma unroll
    for (int r = 0; r < 8; ++r) z[r] = bp + sx[rg * 8 + r][d];
    for (int c4 = 0; c4 < 32; ++c4) {
      float4 w = Wp[c4];
      #pragma unroll
      for (int r = 0; r < 8; ++r) {
        float4 av = *(const float4*)&sa[rg * 8 + r][c4 * 4];
        z[r] += w.x * av.x + w.y * av.y + w.z * av.z + w.w * av.w;
      }
    }
  }
  __syncthreads();
  #pragma unroll
  for (int r = 0; r < 8; ++r) sx[rg * 8 + r][d] = z[r];
  __syncthreads();
  {
    int rt = t >> 4, lane = t & 15;
    float s = 0.f, s2 = 0.f;
    #pragma unroll
    for (int j = 0; j < 8; ++j) { float v = sx[rt][lane + 16 * j]; s += v; s2 += v * v; }
    #pragma unroll
    for (int msk = 1; msk < 16; msk <<= 1) { s += __shfl_xor(s, msk, 16); s2 += __shfl_xor(s2, msk, 16); }
    if (lane == 0) { stats[rt][0] = s * (1.f / 128.f); stats[rt][1] = s2 * (1.f / 128.f); }
  }
  __syncthreads();
  float ln1[8];
  {
    float pg = preg[d], pb = preb[d];
    #pragma unroll
    for (int r = 0; r < 8; ++r) {
      int rr = rg * 8 + r;
      float mu  = stats[rr][0];
      float var = fmaxf(stats[rr][1] - mu * mu, 0.f);
      ln1[r] = (z[r] - mu) * rsqrtf(var + 1e-5f) * pg + pb;
      sln[rr][d] = ln1[r];
    }
  }
  __syncthreads();
  {
    const float4* W1p = (const float4*)W1 + t * 32;
    float hb = b1[t];
    float h[16];
    #pragma unroll
    for (int r = 0; r < 16; ++r) h[r] = hb;
    for (int c4 = 0; c4 < 32; ++c4) {
      float4 w = W1p[c4];
      #pragma unroll
      for (int r = 0; r < 16; ++r) {
        float4 lv = *(const float4*)&sln[r][c4 * 4];
        h[r] += w.x * lv.x + w.y * lv.y + w.z * lv.z + w.w * lv.w;
      }
    }
    #pragma unroll
    for (int r = 0; r < 16; ++r) {
      float hv = h[r];
      sh[r][t] = 0.5f * hv * (1.f + erff(hv * 0.70710678118f));
    }
  }
  __syncthreads();
  float o[8];
  {
    const float4* W2p = (const float4*)W2 + d * 64;
    float b2v = b2[d];
    #pragma unroll
    for (int r = 0; r < 8; ++r) o[r] = ln1[r] + b2v;
    for (int c4 = 0; c4 < 64; ++c4) {
      float4 w = W2p[c4];
      #pragma unroll
      for (int r = 0; r < 8; ++r) {
        float4 hv = *(const float4*)&sh[rg * 8 + r][c4 * 4];
        o[r] += w.x * hv.x + w.y * hv.y + w.z * hv.z + w.w * hv.w;
      }
    }
  }
  __syncthreads();
  #pragma unroll
  for (int r = 0; r < 8; ++r) sx[rg * 8 + r][d] = o[r];
  __syncthreads();
  {
    int rt = t >> 4, lane = t & 15;
    float s = 0.f, s2 = 0.f;
    #pragma unroll
    for (int j = 0; j < 8; ++j) { float v = sx[rt][lane + 16 * j]; s += v; s2 += v * v; }
    #pragma unroll
    for (int msk = 1; msk < 16; msk <<= 1) { s += __shfl_xor(s, msk, 16); s2 += __shfl_xor(s2, msk, 16); }
    if (lane == 0) { stats[rt][0] = s * (1.f / 128.f); stats[rt][1] = s2 * (1.f / 128.f); }
  }
  __syncthreads();
  {
    float pg = postg[d], pb = postb[d];
    #pragma unroll
    for (int r = 0; r < 8; ++r) {
      int rr = rg * 8 + r;
      float mu  = stats[rr][0];
      float var = fmaxf(stats[rr][1] - mu * mu, 0.f);
      sa[rr][d] = (o[r] - mu) * rsqrtf(var + 1e-5f) * pg + pb;
    }
  }
  __syncthreads();
  #pragma unroll
  for (int i = 0; i < 8; ++i) {
    int e = i * 256 + t;
    int dd = e >> 4, qi = e & 15;
    int qq = q0 + qi;
    if (qq < QQ) out[((size_t)b * DIMN + dd) * QQ + qq] = sa[qi][dd];
  }
}

// ---------- launch ----------
extern "C" void kernel_launch(void* const* d_in, const int* in_sizes, int n_in,
                              void* d_out, int out_size, void* d_ws, size_t ws_size,
                              hipStream_t stream) {
  const float* x        = (const float*)d_in[0];
  const float* feature  = (const float*)d_in[1];
  const float* I_inv    = (const float*)d_in[2];
  const float* E_inv    = (const float*)d_in[3];
  const float* bev_grid = (const float*)d_in[4];
  const float* plane    = (const float*)d_in[5];
  const float* W_cam    = (const float*)d_in[6];
  const float* W_img    = (const float*)d_in[7];
  const float* W_bev    = (const float*)d_in[8];
  const float* b_bev    = (const float*)d_in[9];
  const float* fp_g = (const float*)d_in[10];
  const float* fp_b = (const float*)d_in[11];
  const float* fp_m = (const float*)d_in[12];
  const float* fp_v = (const float*)d_in[13];
  const float* fl_g = (const float*)d_in[14];
  const float* fl_b = (const float*)d_in[15];
  const float* fl_m = (const float*)d_in[16];
  const float* fl_v = (const float*)d_in[17];
  const float* W_fproj = (const float*)d_in[18];
  const float* W_flin  = (const float*)d_in[19];
  const float* q_ln_g = (const float*)d_in[20];
  const float* q_ln_b = (const float*)d_in[21];
  const float* Wq = (const float*)d_in[22];
  const float* bq = (const float*)d_in[23];
  const float* k_ln_g = (const float*)d_in[24];
  const float* k_ln_b = (const float*)d_in[25];
  const float* Wk = (const float*)d_in[26];
  const float* bk = (const float*)d_in[27];
  const float* v_ln_g = (const float*)d_in[28];
  const float* v_ln_b = (const float*)d_in[29];
  const float* Wv = (const float*)d_in[30];
  const float* bv = (const float*)d_in[31];
  const float* Wproj = (const float*)d_in[32];
  const float* bproj = (const float*)d_in[33];
  const float* pre_g = (const float*)d_in[34];
  const float* pre_b = (const float*)d_in[35];
  const float* W1 = (const float*)d_in[36];
  const float* b1 = (const float*)d_in[37];
  const float* W2 = (const float*)d_in[38];
  const float* b2 = (const float*)d_in[39];
  const float* post_g = (const float*)d_in[40];
  const float* post_b = (const float*)d_in[41];

  float* ws    = (float*)d_ws;
  float* ce    = ws;                       // 2048
  float* keyb  = ce + 2048;                // 2,580,480
  float* valb  = keyb + 2580480;           // 2,580,480
  float* query = valb + 2580480;           // 3,840,000
  float* aout  = query + 3840000;          // 640,000
  unsigned short* qhB = (unsigned short*)(aout + 640000);  // 3,840,000 u16
  unsigned short* vhB = qhB + 3840000;                     // 2,580,480 u16 (tail OOB spills into khB: safe)
  unsigned short* khB = vhB + 2580480;                     // 2,580,480 u16

  k_cembed<<<12, 128, 0, stream>>>(W_cam, E_inv, ce);
  k_img<<<dim3(KK, 12), 128, 0, stream>>>(I_inv, E_inv, plane, W_img, ce, keyb);
  k_query<<<dim3(QQ, 12), 128, 0, stream>>>(bev_grid, W_bev, b_bev, ce, x, query);
  k_featconv<<<dim3(KK / TP, 12), 256, 0, stream>>>(feature,
      fp_g, fp_b, fp_m, fp_v, fl_g, fl_b, fl_m, fl_v, W_fproj, W_flin, keyb, valb);
  k_lnproj_bf<0><<<(12 * QQ) / ROWS, 128, 0, stream>>>(query, q_ln_g, q_ln_b, Wq, bq, qhB, SCALE);
  k_lnproj_bf<0><<<(12 * KK) / ROWS, 128, 0, stream>>>(keyb, k_ln_g, k_ln_b, Wk, bk, khB, 1.0f);
  k_lnproj_bf<1><<<(12 * KK) / ROWS, 128, 0, stream>>>(valb, v_ln_g, v_ln_b, Wv, bv, vhB, 1.0f);
  k_attn_mfma<<<dim3((QQ + 15) / 16, NHEAD, NB), 512, 0, stream>>>(qhB, khB, vhB, aout);
  k_epi2<<<dim3((QQ + EQ - 1) / EQ, NB), 256, 0, stream>>>(aout, x, Wproj, bproj,
      pre_g, pre_b, W1, b1, W2, b2, post_g, post_b, (float*)d_out);
}

// Round 8
// 581.240 us; speedup vs baseline: 1.2751x; 1.2751x over previous
//
#include <hip/hip_runtime.h>

#define NB    2
#define NCAM  6
#define FD    256
#define KK    1680
#define DIMN  128
#define NHEAD 4
#define DHD   32
#define QQ    2500
#define SCALE 0.17677669529663687f
// SCALE * log2(e): scores computed directly in log2 domain
#define QSCALE ((float)(0.17677669529663687 * 1.4426950408889634))

typedef short bf8 __attribute__((ext_vector_type(8)));
typedef float f4  __attribute__((ext_vector_type(4)));

__device__ __forceinline__ unsigned short f2bf(float f) {
  unsigned int u = __float_as_uint(f);
  unsigned int r = (u + 0x7fffu + ((u >> 16) & 1u)) >> 16;
  return (unsigned short)r;
}

// ---------- helpers ----------
__device__ __forceinline__ float blk_sum128(float v, float* red) {
  #pragma unroll
  for (int o = 32; o > 0; o >>= 1) v += __shfl_down(v, o);
  int t = threadIdx.x;
  if ((t & 63) == 0) red[t >> 6] = v;
  __syncthreads();
  float r = red[0] + red[1];
  __syncthreads();
  return r;
}

// ---------- K1: camera-center embedding ----------
__global__ void k_cembed(const float* __restrict__ W_cam, const float* __restrict__ E_inv,
                         float* __restrict__ ce) {
  int bn = blockIdx.x;
  int d  = threadIdx.x;
  const float* e = E_inv + bn * 16;
  float s = 0.f;
  #pragma unroll
  for (int c = 0; c < 4; ++c) s += W_cam[d * 4 + c] * e[c * 4 + 3];
  ce[bn * 128 + d] = s;
}

// ---------- K2: per-pixel ray embedding (normalized) -> key buffer ----------
__global__ void k_img(const float* __restrict__ I_inv, const float* __restrict__ E_inv,
                      const float* __restrict__ plane, const float* __restrict__ W_img,
                      const float* __restrict__ ce, float* __restrict__ key) {
  __shared__ float red[2];
  int p  = blockIdx.x;
  int bn = blockIdx.y;
  int d  = threadIdx.x;
  const float* Ii = I_inv + bn * 9;
  const float* Ei = E_inv + bn * 16;
  float pl0 = plane[p], pl1 = plane[KK + p], pl2 = plane[2 * KK + p];
  float c0 = Ii[0]*pl0 + Ii[1]*pl1 + Ii[2]*pl2;
  float c1 = Ii[3]*pl0 + Ii[4]*pl1 + Ii[5]*pl2;
  float c2 = Ii[6]*pl0 + Ii[7]*pl1 + Ii[8]*pl2;
  float d0 = Ei[0]*c0 + Ei[1]*c1 + Ei[2]*c2  + Ei[3];
  float d1 = Ei[4]*c0 + Ei[5]*c1 + Ei[6]*c2  + Ei[7];
  float d2 = Ei[8]*c0 + Ei[9]*c1 + Ei[10]*c2 + Ei[11];
  float d3 = Ei[12]*c0 + Ei[13]*c1 + Ei[14]*c2 + Ei[15];
  float v = W_img[d*4]*d0 + W_img[d*4+1]*d1 + W_img[d*4+2]*d2 + W_img[d*4+3]*d3
            - ce[bn * 128 + d];
  float ss = blk_sum128(v * v, red);
  float inv = 1.f / (sqrtf(ss) + 1e-7f);
  key[((size_t)bn * KK + p) * DIMN + d] = v * inv;
}

// ---------- K3: BEV positional embedding + x -> query buffer ----------
__global__ void k_query(const float* __restrict__ bev_grid, const float* __restrict__ W_bev,
                        const float* __restrict__ b_bev, const float* __restrict__ ce,
                        const float* __restrict__ x, float* __restrict__ query) {
  __shared__ float red[2];
  int q  = blockIdx.x;
  int bn = blockIdx.y;
  int b  = bn / NCAM;
  int d  = threadIdx.x;
  float g0 = bev_grid[q], g1 = bev_grid[QQ + q];
  float v = W_bev[d * 2] * g0 + W_bev[d * 2 + 1] * g1 + b_bev[d] - ce[bn * 128 + d];
  float ss = blk_sum128(v * v, red);
  float inv = 1.f / (sqrtf(ss) + 1e-7f);
  query[((size_t)bn * QQ + q) * DIMN + d] = v * inv + x[(size_t)(b * DIMN + d) * QQ + q];
}

// ---------- K4: BN+ReLU + dual 1x1 conv on feature; key += fproj, val = flin ----------
#define TP 16
__global__ void k_featconv(const float* __restrict__ feat,
                           const float* __restrict__ g1c, const float* __restrict__ b1c,
                           const float* __restrict__ m1c, const float* __restrict__ v1c,
                           const float* __restrict__ g2c, const float* __restrict__ b2c,
                           const float* __restrict__ m2c, const float* __restrict__ v2c,
                           const float* __restrict__ Wfp, const float* __restrict__ Wfl,
                           float* __restrict__ key, float* __restrict__ val) {
  __shared__ float sc1[FD], sh1[FD], sc2[FD], sh2[FD];
  __shared__ float t1[FD * (TP + 1)];
  __shared__ float t2[FD * (TP + 1)];
  int tile = blockIdx.x;
  int bn   = blockIdx.y;
  int t    = threadIdx.x;
  int p0   = tile * TP;
  {
    int c = t;
    float s1 = g1c[c] * rsqrtf(v1c[c] + 1e-5f);
    sc1[c] = s1; sh1[c] = b1c[c] - m1c[c] * s1;
    float s2 = g2c[c] * rsqrtf(v2c[c] + 1e-5f);
    sc2[c] = s2; sh2[c] = b2c[c] - m2c[c] * s2;
  }
  __syncthreads();
  const float* fb = feat + (size_t)bn * FD * KK + p0;
  int pp = t & 15, crow = t >> 4;
  #pragma unroll
  for (int i = 0; i < 16; ++i) {
    int c = i * 16 + crow;
    float raw = fb[(size_t)c * KK + pp];
    t1[c * (TP + 1) + pp] = fmaxf(raw * sc1[c] + sh1[c], 0.f);
    t2[c * (TP + 1) + pp] = fmaxf(raw * sc2[c] + sh2[c], 0.f);
  }
  __syncthreads();
  int dd = t & 127;
  const float4* W4 = (const float4*)((t < 128) ? Wfp : Wfl) + dd * 64;
  const float* tl = (t < 128) ? t1 : t2;
  float acc[TP];
  #pragma unroll
  for (int p = 0; p < TP; ++p) acc[p] = 0.f;
  for (int c4 = 0; c4 < 64; ++c4) {
    float4 w = W4[c4];
    const float* r0 = &tl[(c4 * 4 + 0) * (TP + 1)];
    const float* r1 = &tl[(c4 * 4 + 1) * (TP + 1)];
    const float* r2 = &tl[(c4 * 4 + 2) * (TP + 1)];
    const float* r3 = &tl[(c4 * 4 + 3) * (TP + 1)];
    #pragma unroll
    for (int p = 0; p < TP; ++p)
      acc[p] += w.x * r0[p] + w.y * r1[p] + w.z * r2[p] + w.w * r3[p];
  }
  __syncthreads();
  {
    float* dst = (t < 128) ? t1 : t2;
    #pragma unroll
    for (int p = 0; p < TP; ++p) dst[dd * (TP + 1) + p] = acc[p];
  }
  __syncthreads();
  #pragma unroll
  for (int i = 0; i < 16; ++i) {
    int e   = i * 256 + t;
    int ddo = e & 127, po = (e >> 7) & 15, wh = e >> 11;
    size_t addr = ((size_t)bn * KK + p0 + po) * DIMN + ddo;
    float vv = (wh ? t2 : t1)[ddo * (TP + 1) + po];
    if (wh) val[addr] = vv;
    else    key[addr] += vv;
  }
}

// ---------- K5: LayerNorm + 128x128 projection -> bf16 (MODE 0 row-major, MODE 1 V-transposed) ----------
#define ROWS 8
template<int MODE>
__global__ void k_lnproj_bf(const float* __restrict__ in, const float* __restrict__ lng,
                            const float* __restrict__ lnb, const float* __restrict__ W,
                            const float* __restrict__ bias, unsigned short* __restrict__ out,
                            float scale) {
  __shared__ float red[2];
  __shared__ float ln[ROWS][DIMN];
  __shared__ float stats[ROWS][2];
  size_t r0 = (size_t)blockIdx.x * ROWS;
  int t = threadIdx.x;
  float g = lng[t], bb = lnb[t];
  float xv[ROWS];
  #pragma unroll
  for (int r = 0; r < ROWS; ++r) xv[r] = in[(r0 + r) * DIMN + t];
  #pragma unroll
  for (int r = 0; r < ROWS; ++r) {
    float s  = blk_sum128(xv[r], red);
    float s2 = blk_sum128(xv[r] * xv[r], red);
    if (t == 0) { stats[r][0] = s * (1.f / 128.f); stats[r][1] = s2 * (1.f / 128.f); }
  }
  __syncthreads();
  #pragma unroll
  for (int r = 0; r < ROWS; ++r) {
    float mu  = stats[r][0];
    float var = fmaxf(stats[r][1] - mu * mu, 0.f);
    float rin = rsqrtf(var + 1e-5f);
    ln[r][t] = (xv[r] - mu) * rin * g + bb;
  }
  __syncthreads();
  float acc[ROWS];
  float bv = bias[t];
  #pragma unroll
  for (int r = 0; r < ROWS; ++r) acc[r] = bv;
  const float4* W4 = (const float4*)W + t * 32;
  for (int j4 = 0; j4 < 32; ++j4) {
    float4 w = W4[j4];
    #pragma unroll
    for (int r = 0; r < ROWS; ++r)
      acc[r] += w.x * ln[r][j4*4] + w.y * ln[r][j4*4+1] + w.z * ln[r][j4*4+2] + w.w * ln[r][j4*4+3];
  }
  if (MODE == 0) {
    #pragma unroll
    for (int r = 0; r < ROWS; ++r) out[(r0 + r) * DIMN + t] = f2bf(acc[r] * scale);
  } else {
    // V transposed: out[((bn*4+m)*32+d)*1680 + k], 8 consecutive k -> one 16B store
    int bn = (int)(r0 / KK), k0 = (int)(r0 % KK);
    int m = t >> 5, d = t & 31;
    unsigned int u0 = (unsigned int)f2bf(acc[0]) | ((unsigned int)f2bf(acc[1]) << 16);
    unsigned int u1 = (unsigned int)f2bf(acc[2]) | ((unsigned int)f2bf(acc[3]) << 16);
    unsigned int u2 = (unsigned int)f2bf(acc[4]) | ((unsigned int)f2bf(acc[5]) << 16);
    unsigned int u3 = (unsigned int)f2bf(acc[6]) | ((unsigned int)f2bf(acc[7]) << 16);
    uint4 pk = make_uint4(u0, u1, u2, u3);
    *(uint4*)&out[((size_t)((bn * 4 + m) * 32 + d)) * KK + k0] = pk;
  }
}

// ---------- K6: MFMA flash attention, 8-way split-K, online softmax with defer-max ----------
// log2-domain scores (log2e folded into Q scale). Per chunk: lane-local max check via
// __all -> fast path has NO cross-lane ops and NO rescale; slow path (rare) does the
// shuffle-tree max + rescale of o and per-lane l. Sum tree for l runs once at the end.
#define AW 8
#define NCHUNK 53   // ceil(1680/32); chunk 52 has 16 keys
#define THR 8.0f    // log2 domain: p bounded by 2^8
__global__ __launch_bounds__(512)
void k_attn_mfma(const unsigned short* __restrict__ qhB, const unsigned short* __restrict__ khB,
                 const unsigned short* __restrict__ vhB, float* __restrict__ aout) {
  __shared__ unsigned short pls[AW][16 * 40];   // per-wave P transpose buffer
  __shared__ float lds_o[AW][16][32];           // unnormalized o partials
  __shared__ float lds_m[AW][16], lds_l[AW][16];
  int qt = blockIdx.x, m = blockIdx.y, b = blockIdx.z;
  int t = threadIdx.x;
  int w = t >> 6, l = t & 63;
  int c = l & 15, g = l >> 4;
  int q0 = qt * 16;

  bf8 qf[NCAM];
  #pragma unroll
  for (int n = 0; n < NCAM; ++n) {
    int q = q0 + c;
    if (q < QQ)
      qf[n] = *(const bf8*)&qhB[((size_t)(b * NCAM + n) * QQ + q) * DIMN + m * DHD + g * 8];
    else
      qf[n] = (bf8)0;
  }
  const f4 z4 = {0.f, 0.f, 0.f, 0.f};
  f4 o0 = z4, o1 = z4;
  float mrun[4], lp[4];
  #pragma unroll
  for (int i = 0; i < 4; ++i) { mrun[i] = -1e30f; lp[i] = 0.f; }

  for (int n = 0; n < NCAM; ++n) {
    const unsigned short* kb = khB + (size_t)(b * NCAM + n) * KK * DIMN + m * DHD;
    const unsigned short* vb = vhB + (size_t)((b * NCAM + n) * NHEAD + m) * DHD * KK;
    bf8 qa = qf[n];
    for (int j = w; j < NCHUNK; j += AW) {
      int k0 = j * 32;
      bool tail = (j == NCHUNK - 1);
      bf8 kf0 = *(const bf8*)&kb[(size_t)(k0 + c) * DIMN + g * 8];
      bf8 vf0 = *(const bf8*)&vb[(size_t)c * KK + k0 + g * 8];
      bf8 vf1 = *(const bf8*)&vb[(size_t)(16 + c) * KK + k0 + g * 8];
      f4 s0 = __builtin_amdgcn_mfma_f32_16x16x32_bf16(qa, kf0, z4, 0, 0, 0);
      f4 s1;
      if (!tail) {
        bf8 kf1 = *(const bf8*)&kb[(size_t)(k0 + 16 + c) * DIMN + g * 8];
        s1 = __builtin_amdgcn_mfma_f32_16x16x32_bf16(qa, kf1, z4, 0, 0, 0);
      } else {
        s1 = (f4){-1e30f, -1e30f, -1e30f, -1e30f};
      }
      // lane-local max + defer check (wave-uniform branch)
      float lm[4];
      #pragma unroll
      for (int i = 0; i < 4; ++i) lm[i] = fmaxf(s0[i], s1[i]);
      bool ok = (lm[0] <= mrun[0] + THR) && (lm[1] <= mrun[1] + THR)
             && (lm[2] <= mrun[2] + THR) && (lm[3] <= mrun[3] + THR);
      if (!__all(ok)) {
        #pragma unroll
        for (int i = 0; i < 4; ++i) {
          float tm = lm[i];
          #pragma unroll
          for (int msk = 1; msk < 16; msk <<= 1) tm = fmaxf(tm, __shfl_xor(tm, msk, 16));
          float mn = fmaxf(mrun[i], tm);
          float al = __builtin_amdgcn_exp2f(mrun[i] - mn);
          mrun[i] = mn;
          lp[i] *= al;
          o0[i] *= al; o1[i] *= al;
        }
      }
      #pragma unroll
      for (int i = 0; i < 4; ++i) {
        float p0 = __builtin_amdgcn_exp2f(s0[i] - mrun[i]);
        float p1 = __builtin_amdgcn_exp2f(s1[i] - mrun[i]);   // tail: exp2(-inf) = 0
        lp[i] += p0 + p1;
        pls[w][(4 * g + i) * 40 + c]      = f2bf(p0);
        pls[w][(4 * g + i) * 40 + 16 + c] = f2bf(p1);
      }
      bf8 pa = *(const bf8*)&pls[w][c * 40 + g * 8];
      o0 = __builtin_amdgcn_mfma_f32_16x16x32_bf16(pa, vf0, o0, 0, 0, 0);
      o1 = __builtin_amdgcn_mfma_f32_16x16x32_bf16(pa, vf1, o1, 0, 0, 0);
    }
  }
  // single sum tree per row for the per-lane l partials
  #pragma unroll
  for (int i = 0; i < 4; ++i) {
    #pragma unroll
    for (int msk = 1; msk < 16; msk <<= 1) lp[i] += __shfl_xor(lp[i], msk, 16);
  }
  // dump per-wave partials (unnormalized)
  #pragma unroll
  for (int i = 0; i < 4; ++i) {
    int qr = 4 * g + i;
    if (c == 0) { lds_m[w][qr] = mrun[i]; lds_l[w][qr] = lp[i]; }
    lds_o[w][qr][c]      = o0[i];
    lds_o[w][qr][16 + c] = o1[i];
  }
  __syncthreads();
  // merge: 512 threads = 16 q x 32 d (log2-domain m)
  {
    int q = t >> 5, d = t & 31;
    float mg = -1e30f;
    #pragma unroll
    for (int ww = 0; ww < AW; ++ww) mg = fmaxf(mg, lds_m[ww][q]);
    float lg = 0.f, og = 0.f;
    #pragma unroll
    for (int ww = 0; ww < AW; ++ww) {
      float sc = __builtin_amdgcn_exp2f(lds_m[ww][q] - mg);
      lg += lds_l[ww][q] * sc;
      og += lds_o[ww][q][d] * sc;
    }
    int qq = q0 + q;
    if (qq < QQ)
      aout[((size_t)b * QQ + qq) * DIMN + m * DHD + d] = og / lg;
  }
}

// ---------- K7: tiled epilogue: 16 q / block, 256 threads ----------
#define EQ 16
#define EPAD 4
__global__ __launch_bounds__(256)
void k_epi2(const float* __restrict__ a, const float* __restrict__ x,
            const float* __restrict__ Wproj, const float* __restrict__ bproj,
            const float* __restrict__ preg, const float* __restrict__ preb,
            const float* __restrict__ W1, const float* __restrict__ b1,
            const float* __restrict__ W2, const float* __restrict__ b2,
            const float* __restrict__ postg, const float* __restrict__ postb,
            float* __restrict__ out) {
  __shared__ float sa[EQ][DIMN + EPAD];    // a tile, later final-output transpose buffer
  __shared__ float sx[EQ][DIMN + EPAD];    // x tile, later reduction scratch
  __shared__ float sln[EQ][DIMN + EPAD];   // preLN result
  __shared__ float sh[EQ][2 * DIMN];       // MLP hidden
  __shared__ float stats[EQ][2];
  int q0 = blockIdx.x * EQ;
  int b  = blockIdx.y;
  int t  = threadIdx.x;
  int d  = t & 127, rg = t >> 7;

  #pragma unroll
  for (int i = 0; i < 8; ++i) {
    int e = i * 256 + t;
    int q = e >> 7, dd = e & 127;
    int qq = q0 + q;
    sa[q][dd] = (qq < QQ) ? a[((size_t)b * QQ + qq) * DIMN + dd] : 0.f;
  }
  #pragma unroll
  for (int i = 0; i < 8; ++i) {
    int e = i * 256 + t;
    int dd = e >> 4, qi = e & 15;
    int qq = q0 + qi;
    sx[qi][dd] = (qq < QQ) ? x[((size_t)b * DIMN + dd) * QQ + qq] : 0.f;
  }
  __syncthreads();

  float z[8];
  {
    const float4* Wp = (const float4*)Wproj + d * 32;
    float bp = bproj[d];
    #pragma unroll
    for (int r = 0; r < 8; ++r) z[r] = bp + sx[rg * 8 + r][d];
    for (int c4 = 0; c4 < 32; ++c4) {
      float4 w = Wp[c4];
      #pragma unroll
      for (int r = 0; r < 8; ++r) {
        float4 av = *(const float4*)&sa[rg * 8 + r][c4 * 4];
        z[r] += w.x * av.x + w.y * av.y + w.z * av.z + w.w * av.w;
      }
    }
  }
  __syncthreads();
  #pragma unroll
  for (int r = 0; r < 8; ++r) sx[rg * 8 + r][d] = z[r];
  __syncthreads();
  {
    int rt = t >> 4, lane = t & 15;
    float s = 0.f, s2 = 0.f;
    #pragma unroll
    for (int j = 0; j < 8; ++j) { float v = sx[rt][lane + 16 * j]; s += v; s2 += v * v; }
    #pragma unroll
    for (int msk = 1; msk < 16; msk <<= 1) { s += __shfl_xor(s, msk, 16); s2 += __shfl_xor(s2, msk, 16); }
    if (lane == 0) { stats[rt][0] = s * (1.f / 128.f); stats[rt][1] = s2 * (1.f / 128.f); }
  }
  __syncthreads();
  float ln1[8];
  {
    float pg = preg[d], pb = preb[d];
    #pragma unroll
    for (int r = 0; r < 8; ++r) {
      int rr = rg * 8 + r;
      float mu  = stats[rr][0];
      float var = fmaxf(stats[rr][1] - mu * mu, 0.f);
      ln1[r] = (z[r] - mu) * rsqrtf(var + 1e-5f) * pg + pb;
      sln[rr][d] = ln1[r];
    }
  }
  __syncthreads();
  {
    const float4* W1p = (const float4*)W1 + t * 32;
    float hb = b1[t];
    float h[16];
    #pragma unroll
    for (int r = 0; r < 16; ++r) h[r] = hb;
    for (int c4 = 0; c4 < 32; ++c4) {
      float4 w = W1p[c4];
      #pragma unroll
      for (int r = 0; r < 16; ++r) {
        float4 lv = *(const float4*)&sln[r][c4 * 4];
        h[r] += w.x * lv.x + w.y * lv.y + w.z * lv.z + w.w * lv.w;
      }
    }
    #pragma unroll
    for (int r = 0; r < 16; ++r) {
      float hv = h[r];
      sh[r][t] = 0.5f * hv * (1.f + erff(hv * 0.70710678118f));
    }
  }
  __syncthreads();
  float o[8];
  {
    const float4* W2p = (const float4*)W2 + d * 64;
    float b2v = b2[d];
    #pragma unroll
    for (int r = 0; r < 8; ++r) o[r] = ln1[r] + b2v;
    for (int c4 = 0; c4 < 64; ++c4) {
      float4 w = W2p[c4];
      #pragma unroll
      for (int r = 0; r < 8; ++r) {
        float4 hv = *(const float4*)&sh[rg * 8 + r][c4 * 4];
        o[r] += w.x * hv.x + w.y * hv.y + w.z * hv.z + w.w * hv.w;
      }
    }
  }
  __syncthreads();
  #pragma unroll
  for (int r = 0; r < 8; ++r) sx[rg * 8 + r][d] = o[r];
  __syncthreads();
  {
    int rt = t >> 4, lane = t & 15;
    float s = 0.f, s2 = 0.f;
    #pragma unroll
    for (int j = 0; j < 8; ++j) { float v = sx[rt][lane + 16 * j]; s += v; s2 += v * v; }
    #pragma unroll
    for (int msk = 1; msk < 16; msk <<= 1) { s += __shfl_xor(s, msk, 16); s2 += __shfl_xor(s2, msk, 16); }
    if (lane == 0) { stats[rt][0] = s * (1.f / 128.f); stats[rt][1] = s2 * (1.f / 128.f); }
  }
  __syncthreads();
  {
    float pg = postg[d], pb = postb[d];
    #pragma unroll
    for (int r = 0; r < 8; ++r) {
      int rr = rg * 8 + r;
      float mu  = stats[rr][0];
      float var = fmaxf(stats[rr][1] - mu * mu, 0.f);
      sa[rr][d] = (o[r] - mu) * rsqrtf(var + 1e-5f) * pg + pb;
    }
  }
  __syncthreads();
  #pragma unroll
  for (int i = 0; i < 8; ++i) {
    int e = i * 256 + t;
    int dd = e >> 4, qi = e & 15;
    int qq = q0 + qi;
    if (qq < QQ) out[((size_t)b * DIMN + dd) * QQ + qq] = sa[qi][dd];
  }
}

// ---------- launch ----------
extern "C" void kernel_launch(void* const* d_in, const int* in_sizes, int n_in,
                              void* d_out, int out_size, void* d_ws, size_t ws_size,
                              hipStream_t stream) {
  const float* x        = (const float*)d_in[0];
  const float* feature  = (const float*)d_in[1];
  const float* I_inv    = (const float*)d_in[2];
  const float* E_inv    = (const float*)d_in[3];
  const float* bev_grid = (const float*)d_in[4];
  const float* plane    = (const float*)d_in[5];
  const float* W_cam    = (const float*)d_in[6];
  const float* W_img    = (const float*)d_in[7];
  const float* W_bev    = (const float*)d_in[8];
  const float* b_bev    = (const float*)d_in[9];
  const float* fp_g = (const float*)d_in[10];
  const float* fp_b = (const float*)d_in[11];
  const float* fp_m = (const float*)d_in[12];
  const float* fp_v = (const float*)d_in[13];
  const float* fl_g = (const float*)d_in[14];
  const float* fl_b = (const float*)d_in[15];
  const float* fl_m = (const float*)d_in[16];
  const float* fl_v = (const float*)d_in[17];
  const float* W_fproj = (const float*)d_in[18];
  const float* W_flin  = (const float*)d_in[19];
  const float* q_ln_g = (const float*)d_in[20];
  const float* q_ln_b = (const float*)d_in[21];
  const float* Wq = (const float*)d_in[22];
  const float* bq = (const float*)d_in[23];
  const float* k_ln_g = (const float*)d_in[24];
  const float* k_ln_b = (const float*)d_in[25];
  const float* Wk = (const float*)d_in[26];
  const float* bk = (const float*)d_in[27];
  const float* v_ln_g = (const float*)d_in[28];
  const float* v_ln_b = (const float*)d_in[29];
  const float* Wv = (const float*)d_in[30];
  const float* bv = (const float*)d_in[31];
  const float* Wproj = (const float*)d_in[32];
  const float* bproj = (const float*)d_in[33];
  const float* pre_g = (const float*)d_in[34];
  const float* pre_b = (const float*)d_in[35];
  const float* W1 = (const float*)d_in[36];
  const float* b1 = (const float*)d_in[37];
  const float* W2 = (const float*)d_in[38];
  const float* b2 = (const float*)d_in[39];
  const float* post_g = (const float*)d_in[40];
  const float* post_b = (const float*)d_in[41];

  float* ws    = (float*)d_ws;
  float* ce    = ws;                       // 2048
  float* keyb  = ce + 2048;                // 2,580,480
  float* valb  = keyb + 2580480;           // 2,580,480
  float* query = valb + 2580480;           // 3,840,000
  float* aout  = query + 3840000;          // 640,000
  unsigned short* qhB = (unsigned short*)(aout + 640000);  // 3,840,000 u16
  unsigned short* vhB = qhB + 3840000;                     // 2,580,480 u16 (tail OOB spills into khB: safe)
  unsigned short* khB = vhB + 2580480;                     // 2,580,480 u16

  k_cembed<<<12, 128, 0, stream>>>(W_cam, E_inv, ce);
  k_img<<<dim3(KK, 12), 128, 0, stream>>>(I_inv, E_inv, plane, W_img, ce, keyb);
  k_query<<<dim3(QQ, 12), 128, 0, stream>>>(bev_grid, W_bev, b_bev, ce, x, query);
  k_featconv<<<dim3(KK / TP, 12), 256, 0, stream>>>(feature,
      fp_g, fp_b, fp_m, fp_v, fl_g, fl_b, fl_m, fl_v, W_fproj, W_flin, keyb, valb);
  k_lnproj_bf<0><<<(12 * QQ) / ROWS, 128, 0, stream>>>(query, q_ln_g, q_ln_b, Wq, bq, qhB, QSCALE);
  k_lnproj_bf<0><<<(12 * KK) / ROWS, 128, 0, stream>>>(keyb, k_ln_g, k_ln_b, Wk, bk, khB, 1.0f);
  k_lnproj_bf<1><<<(12 * KK) / ROWS, 128, 0, stream>>>(valb, v_ln_g, v_ln_b, Wv, bv, vhB, 1.0f);
  k_attn_mfma<<<dim3((QQ + 15) / 16, NHEAD, NB), 512, 0, stream>>>(qhB, khB, vhB, aout);
  k_epi2<<<dim3((QQ + EQ - 1) / EQ, NB), 256, 0, stream>>>(aout, x, Wproj, bproj,
      pre_g, pre_b, W1, b1, W2, b2, post_g, post_b, (float*)d_out);
}

// Round 9
// 497.199 us; speedup vs baseline: 1.4907x; 1.1690x over previous
//
#include <hip/hip_runtime.h>

#define NB    2
#define NCAM  6
#define FD    256
#define KK    1680
#define DIMN  128
#define NHEAD 4
#define DHD   32
#define QQ    2500
#define SCALE 0.17677669529663687f
// SCALE * log2(e): scores computed directly in log2 domain
#define QSCALE ((float)(0.17677669529663687 * 1.4426950408889634))

typedef short bf8 __attribute__((ext_vector_type(8)));
typedef float f4  __attribute__((ext_vector_type(4)));

__device__ __forceinline__ unsigned short f2bf(float f) {
  unsigned int u = __float_as_uint(f);
  unsigned int r = (u + 0x7fffu + ((u >> 16) & 1u)) >> 16;
  return (unsigned short)r;
}

// ---------- helpers ----------
__device__ __forceinline__ float blk_sum128(float v, float* red) {
  #pragma unroll
  for (int o = 32; o > 0; o >>= 1) v += __shfl_down(v, o);
  int t = threadIdx.x;
  if ((t & 63) == 0) red[t >> 6] = v;
  __syncthreads();
  float r = red[0] + red[1];
  __syncthreads();
  return r;
}

// ---------- K0: convert the 5 weight matrices to bf16 (once per launch) ----------
__global__ __launch_bounds__(256)
void k_cvtw(const float* __restrict__ a0, const float* __restrict__ a1,
            const float* __restrict__ a2, const float* __restrict__ a3,
            const float* __restrict__ a4,
            unsigned short* __restrict__ b0, unsigned short* __restrict__ b1,
            unsigned short* __restrict__ b2, unsigned short* __restrict__ b3,
            unsigned short* __restrict__ b4) {
  int bid = blockIdx.x;
  const float* s; unsigned short* d; int off;
  if (bid < 32)      { s = a0; d = b0; off = bid; }
  else if (bid < 64) { s = a1; d = b1; off = bid - 32; }
  else if (bid < 80) { s = a2; d = b2; off = bid - 64; }
  else if (bid < 96) { s = a3; d = b3; off = bid - 80; }
  else               { s = a4; d = b4; off = bid - 96; }
  int i = off * 1024 + threadIdx.x * 4;
  float4 v = *(const float4*)&s[i];
  uint2 pk = make_uint2((unsigned)f2bf(v.x) | ((unsigned)f2bf(v.y) << 16),
                        (unsigned)f2bf(v.z) | ((unsigned)f2bf(v.w) << 16));
  *(uint2*)&d[i] = pk;
}

// ---------- K1: camera-center embedding ----------
__global__ void k_cembed(const float* __restrict__ W_cam, const float* __restrict__ E_inv,
                         float* __restrict__ ce) {
  int bn = blockIdx.x;
  int d  = threadIdx.x;
  const float* e = E_inv + bn * 16;
  float s = 0.f;
  #pragma unroll
  for (int c = 0; c < 4; ++c) s += W_cam[d * 4 + c] * e[c * 4 + 3];
  ce[bn * 128 + d] = s;
}

// ---------- K2: per-pixel ray embedding (normalized) -> key buffer ----------
__global__ void k_img(const float* __restrict__ I_inv, const float* __restrict__ E_inv,
                      const float* __restrict__ plane, const float* __restrict__ W_img,
                      const float* __restrict__ ce, float* __restrict__ key) {
  __shared__ float red[2];
  int p  = blockIdx.x;
  int bn = blockIdx.y;
  int d  = threadIdx.x;
  const float* Ii = I_inv + bn * 9;
  const float* Ei = E_inv + bn * 16;
  float pl0 = plane[p], pl1 = plane[KK + p], pl2 = plane[2 * KK + p];
  float c0 = Ii[0]*pl0 + Ii[1]*pl1 + Ii[2]*pl2;
  float c1 = Ii[3]*pl0 + Ii[4]*pl1 + Ii[5]*pl2;
  float c2 = Ii[6]*pl0 + Ii[7]*pl1 + Ii[8]*pl2;
  float d0 = Ei[0]*c0 + Ei[1]*c1 + Ei[2]*c2  + Ei[3];
  float d1 = Ei[4]*c0 + Ei[5]*c1 + Ei[6]*c2  + Ei[7];
  float d2 = Ei[8]*c0 + Ei[9]*c1 + Ei[10]*c2 + Ei[11];
  float d3 = Ei[12]*c0 + Ei[13]*c1 + Ei[14]*c2 + Ei[15];
  float v = W_img[d*4]*d0 + W_img[d*4+1]*d1 + W_img[d*4+2]*d2 + W_img[d*4+3]*d3
            - ce[bn * 128 + d];
  float ss = blk_sum128(v * v, red);
  float inv = 1.f / (sqrtf(ss) + 1e-7f);
  key[((size_t)bn * KK + p) * DIMN + d] = v * inv;
}

// ---------- K3: BEV positional embedding + x -> query buffer ----------
__global__ void k_query(const float* __restrict__ bev_grid, const float* __restrict__ W_bev,
                        const float* __restrict__ b_bev, const float* __restrict__ ce,
                        const float* __restrict__ x, float* __restrict__ query) {
  __shared__ float red[2];
  int q  = blockIdx.x;
  int bn = blockIdx.y;
  int b  = bn / NCAM;
  int d  = threadIdx.x;
  float g0 = bev_grid[q], g1 = bev_grid[QQ + q];
  float v = W_bev[d * 2] * g0 + W_bev[d * 2 + 1] * g1 + b_bev[d] - ce[bn * 128 + d];
  float ss = blk_sum128(v * v, red);
  float inv = 1.f / (sqrtf(ss) + 1e-7f);
  query[((size_t)bn * QQ + q) * DIMN + d] = v * inv + x[(size_t)(b * DIMN + d) * QQ + q];
}

// ---------- K4: BN+ReLU + dual 1x1 conv via MFMA; key += fproj, val = flin ----------
// 64 positions/block, 4 waves (16 pos each). A = bf16 activations (LDS),
// B = bf16 weight rows streamed from L2. D[pos][dout] f32 epilogue.
#define FTP 64
#define FSTR 264   // u16 row stride: 16B-aligned, 132 dwords (bank stride 4)
__global__ __launch_bounds__(256)
void k_featconv_mfma(const float* __restrict__ feat,
                     const float* __restrict__ g1c, const float* __restrict__ b1c,
                     const float* __restrict__ m1c, const float* __restrict__ v1c,
                     const float* __restrict__ g2c, const float* __restrict__ b2c,
                     const float* __restrict__ m2c, const float* __restrict__ v2c,
                     const unsigned short* __restrict__ WfpB,
                     const unsigned short* __restrict__ WflB,
                     float* __restrict__ key, float* __restrict__ val) {
  __shared__ unsigned short act[FTP * FSTR];
  __shared__ float scs[2][FD], shs[2][FD];
  int tile = blockIdx.x, bn = blockIdx.y;
  int p0 = tile * FTP;
  int t = threadIdx.x;
  {
    float s1 = g1c[t] * rsqrtf(v1c[t] + 1e-5f);
    scs[0][t] = s1; shs[0][t] = b1c[t] - m1c[t] * s1;
    float s2 = g2c[t] * rsqrtf(v2c[t] + 1e-5f);
    scs[1][t] = s2; shs[1][t] = b2c[t] - m2c[t] * s2;
  }
  int w = t >> 6, l = t & 63, c = l & 15, g = l >> 4;
  const float* fb = feat + (size_t)bn * FD * KK;
  for (int var = 0; var < 2; ++var) {
    __syncthreads();
    // stage: BN+ReLU -> bf16, [pos][cin]
    #pragma unroll
    for (int it = 0; it < 16; ++it) {
      int e   = it * 256 + t;
      int cin = e >> 4;
      int pq  = (e & 15) * 4;
      int pp  = min(p0 + pq, KK - 4);          // tail clamp; garbage masked at store
      float4 r = *(const float4*)&fb[(size_t)cin * KK + pp];
      float s = scs[var][cin], h = shs[var][cin];
      act[(pq + 0) * FSTR + cin] = f2bf(fmaxf(r.x * s + h, 0.f));
      act[(pq + 1) * FSTR + cin] = f2bf(fmaxf(r.y * s + h, 0.f));
      act[(pq + 2) * FSTR + cin] = f2bf(fmaxf(r.z * s + h, 0.f));
      act[(pq + 3) * FSTR + cin] = f2bf(fmaxf(r.w * s + h, 0.f));
    }
    __syncthreads();
    const unsigned short* W = var ? WflB : WfpB;
    bf8 af[8];
    #pragma unroll
    for (int kk = 0; kk < 8; ++kk)
      af[kk] = *(const bf8*)&act[(w * 16 + c) * FSTR + kk * 32 + g * 8];
    f4 acc[8];
    #pragma unroll
    for (int grp = 0; grp < 8; ++grp) {
      f4 a = {0.f, 0.f, 0.f, 0.f};
      #pragma unroll
      for (int kk = 0; kk < 8; ++kk) {
        bf8 bfr = *(const bf8*)&W[(grp * 16 + c) * FD + kk * 32 + g * 8];
        a = __builtin_amdgcn_mfma_f32_16x16x32_bf16(af[kk], bfr, a, 0, 0, 0);
      }
      acc[grp] = a;
    }
    #pragma unroll
    for (int i = 0; i < 4; ++i) {
      int pos = p0 + w * 16 + 4 * g + i;
      if (pos < KK) {
        size_t base = ((size_t)bn * KK + pos) * DIMN + c;
        if (var == 0) {
          #pragma unroll
          for (int grp = 0; grp < 8; ++grp) key[base + grp * 16] += acc[grp][i];
        } else {
          #pragma unroll
          for (int grp = 0; grp < 8; ++grp) val[base + grp * 16] = acc[grp][i];
        }
      }
    }
  }
}

// ---------- K5: LayerNorm (f32) + 128x128 projection via MFMA -> bf16 ----------
// MODE 0: row-major out, optional scale. MODE 1: V-transposed out.
// 64 tokens/block, 4 waves; LN stats via width-4 shuffles (no LDS round trip).
#define LSTR 136   // u16 row stride: 16B-aligned, 68 dwords (bank stride 4)
template<int MODE>
__global__ __launch_bounds__(256)
void k_lnproj_mfma(const float* __restrict__ in, int nrows,
                   const float* __restrict__ lng, const float* __restrict__ lnbb,
                   const unsigned short* __restrict__ WB, const float* __restrict__ bias,
                   float scale, unsigned short* __restrict__ out) {
  __shared__ unsigned short lnb[64 * LSTR];
  int tile = blockIdx.x, bn = blockIdx.y;
  int t = threadIdx.x;
  int r0loc = tile * 64;
  int valid = nrows - r0loc; if (valid > 64) valid = 64;
  size_t gr0 = (size_t)bn * nrows + r0loc;
  int tk = t >> 2, qr = t & 3;
  int tkc = (tk < valid) ? tk : (valid - 1);    // clamp; garbage rows masked at store
  const float* ip = &in[(gr0 + tkc) * DIMN + qr * 32];
  float xv[32];
  #pragma unroll
  for (int j = 0; j < 8; ++j) {
    float4 v = *(const float4*)&ip[j * 4];
    xv[j*4] = v.x; xv[j*4+1] = v.y; xv[j*4+2] = v.z; xv[j*4+3] = v.w;
  }
  float s = 0.f, s2 = 0.f;
  #pragma unroll
  for (int j = 0; j < 32; ++j) { s += xv[j]; s2 += xv[j] * xv[j]; }
  s  += __shfl_xor(s, 1, 4);  s  += __shfl_xor(s, 2, 4);
  s2 += __shfl_xor(s2, 1, 4); s2 += __shfl_xor(s2, 2, 4);
  float mu  = s * (1.f / 128.f);
  float var = fmaxf(s2 * (1.f / 128.f) - mu * mu, 0.f);
  float rin = rsqrtf(var + 1e-5f);
  #pragma unroll
  for (int j4 = 0; j4 < 8; ++j4) {
    int d = qr * 32 + j4 * 4;
    float4 gv = *(const float4*)&lng[d];
    float4 bv = *(const float4*)&lnbb[d];
    float l0 = (xv[j4*4+0] - mu) * rin * gv.x + bv.x;
    float l1 = (xv[j4*4+1] - mu) * rin * gv.y + bv.y;
    float l2 = (xv[j4*4+2] - mu) * rin * gv.z + bv.z;
    float l3 = (xv[j4*4+3] - mu) * rin * gv.w + bv.w;
    uint2 pk = make_uint2((unsigned)f2bf(l0) | ((unsigned)f2bf(l1) << 16),
                          (unsigned)f2bf(l2) | ((unsigned)f2bf(l3) << 16));
    *(uint2*)&lnb[tk * LSTR + d] = pk;
  }
  __syncthreads();
  int w = t >> 6, l = t & 63, c = l & 15, g = l >> 4;
  bf8 af[4];
  #pragma unroll
  for (int kk = 0; kk < 4; ++kk)
    af[kk] = *(const bf8*)&lnb[(w * 16 + c) * LSTR + kk * 32 + g * 8];
  f4 acc[8];
  #pragma unroll
  for (int grp = 0; grp < 8; ++grp) {
    f4 a = {0.f, 0.f, 0.f, 0.f};
    #pragma unroll
    for (int kk = 0; kk < 4; ++kk) {
      bf8 bfr = *(const bf8*)&WB[(grp * 16 + c) * DIMN + kk * 32 + g * 8];
      a = __builtin_amdgcn_mfma_f32_16x16x32_bf16(af[kk], bfr, a, 0, 0, 0);
    }
    acc[grp] = a;
  }
  if (MODE == 0) {
    #pragma unroll
    for (int grp = 0; grp < 8; ++grp) {
      float bv = bias[grp * 16 + c];
      #pragma unroll
      for (int i = 0; i < 4; ++i) {
        int rr = w * 16 + 4 * g + i;
        if (rr < valid)
          out[(gr0 + rr) * DIMN + grp * 16 + c] = f2bf((acc[grp][i] + bv) * scale);
      }
    }
  } else {
    // write own rows back into lnb as bf16 output (wave-disjoint rows), then transpose-store
    #pragma unroll
    for (int grp = 0; grp < 8; ++grp) {
      float bv = bias[grp * 16 + c];
      #pragma unroll
      for (int i = 0; i < 4; ++i)
        lnb[(w * 16 + 4 * g + i) * LSTR + grp * 16 + c] = f2bf(acc[grp][i] + bv);
    }
    __syncthreads();
    #pragma unroll
    for (int it = 0; it < 32; ++it) {
      int e = it * 256 + t;
      int dout = e >> 6, tok = e & 63;
      if (tok < valid)
        out[((size_t)(bn * 4 + (dout >> 5)) * 32 + (dout & 31)) * KK + r0loc + tok]
            = lnb[tok * LSTR + dout];
    }
  }
}

// ---------- K6: MFMA flash attention, 8-way split-K, online softmax with defer-max ----------
#define AW 8
#define NCHUNK 53   // ceil(1680/32); chunk 52 has 16 keys
#define THR 8.0f    // log2 domain: p bounded by 2^8
__global__ __launch_bounds__(512)
void k_attn_mfma(const unsigned short* __restrict__ qhB, const unsigned short* __restrict__ khB,
                 const unsigned short* __restrict__ vhB, float* __restrict__ aout) {
  __shared__ unsigned short pls[AW][16 * 40];   // per-wave P transpose buffer
  __shared__ float lds_o[AW][16][32];           // unnormalized o partials
  __shared__ float lds_m[AW][16], lds_l[AW][16];
  int qt = blockIdx.x, m = blockIdx.y, b = blockIdx.z;
  int t = threadIdx.x;
  int w = t >> 6, l = t & 63;
  int c = l & 15, g = l >> 4;
  int q0 = qt * 16;

  bf8 qf[NCAM];
  #pragma unroll
  for (int n = 0; n < NCAM; ++n) {
    int q = q0 + c;
    if (q < QQ)
      qf[n] = *(const bf8*)&qhB[((size_t)(b * NCAM + n) * QQ + q) * DIMN + m * DHD + g * 8];
    else
      qf[n] = (bf8)0;
  }
  const f4 z4 = {0.f, 0.f, 0.f, 0.f};
  f4 o0 = z4, o1 = z4;
  float mrun[4], lp[4];
  #pragma unroll
  for (int i = 0; i < 4; ++i) { mrun[i] = -1e30f; lp[i] = 0.f; }

  for (int n = 0; n < NCAM; ++n) {
    const unsigned short* kb = khB + (size_t)(b * NCAM + n) * KK * DIMN + m * DHD;
    const unsigned short* vb = vhB + (size_t)((b * NCAM + n) * NHEAD + m) * DHD * KK;
    bf8 qa = qf[n];
    for (int j = w; j < NCHUNK; j += AW) {
      int k0 = j * 32;
      bool tail = (j == NCHUNK - 1);
      bf8 kf0 = *(const bf8*)&kb[(size_t)(k0 + c) * DIMN + g * 8];
      bf8 vf0 = *(const bf8*)&vb[(size_t)c * KK + k0 + g * 8];
      bf8 vf1 = *(const bf8*)&vb[(size_t)(16 + c) * KK + k0 + g * 8];
      f4 s0 = __builtin_amdgcn_mfma_f32_16x16x32_bf16(qa, kf0, z4, 0, 0, 0);
      f4 s1;
      if (!tail) {
        bf8 kf1 = *(const bf8*)&kb[(size_t)(k0 + 16 + c) * DIMN + g * 8];
        s1 = __builtin_amdgcn_mfma_f32_16x16x32_bf16(qa, kf1, z4, 0, 0, 0);
      } else {
        s1 = (f4){-1e30f, -1e30f, -1e30f, -1e30f};
      }
      float lm[4];
      #pragma unroll
      for (int i = 0; i < 4; ++i) lm[i] = fmaxf(s0[i], s1[i]);
      bool ok = (lm[0] <= mrun[0] + THR) && (lm[1] <= mrun[1] + THR)
             && (lm[2] <= mrun[2] + THR) && (lm[3] <= mrun[3] + THR);
      if (!__all(ok)) {
        #pragma unroll
        for (int i = 0; i < 4; ++i) {
          float tm = lm[i];
          #pragma unroll
          for (int msk = 1; msk < 16; msk <<= 1) tm = fmaxf(tm, __shfl_xor(tm, msk, 16));
          float mn = fmaxf(mrun[i], tm);
          float al = __builtin_amdgcn_exp2f(mrun[i] - mn);
          mrun[i] = mn;
          lp[i] *= al;
          o0[i] *= al; o1[i] *= al;
        }
      }
      #pragma unroll
      for (int i = 0; i < 4; ++i) {
        float p0 = __builtin_amdgcn_exp2f(s0[i] - mrun[i]);
        float p1 = __builtin_amdgcn_exp2f(s1[i] - mrun[i]);   // tail: exp2(-inf) = 0
        lp[i] += p0 + p1;
        pls[w][(4 * g + i) * 40 + c]      = f2bf(p0);
        pls[w][(4 * g + i) * 40 + 16 + c] = f2bf(p1);
      }
      bf8 pa = *(const bf8*)&pls[w][c * 40 + g * 8];
      o0 = __builtin_amdgcn_mfma_f32_16x16x32_bf16(pa, vf0, o0, 0, 0, 0);
      o1 = __builtin_amdgcn_mfma_f32_16x16x32_bf16(pa, vf1, o1, 0, 0, 0);
    }
  }
  #pragma unroll
  for (int i = 0; i < 4; ++i) {
    #pragma unroll
    for (int msk = 1; msk < 16; msk <<= 1) lp[i] += __shfl_xor(lp[i], msk, 16);
  }
  #pragma unroll
  for (int i = 0; i < 4; ++i) {
    int qr = 4 * g + i;
    if (c == 0) { lds_m[w][qr] = mrun[i]; lds_l[w][qr] = lp[i]; }
    lds_o[w][qr][c]      = o0[i];
    lds_o[w][qr][16 + c] = o1[i];
  }
  __syncthreads();
  {
    int q = t >> 5, d = t & 31;
    float mg = -1e30f;
    #pragma unroll
    for (int ww = 0; ww < AW; ++ww) mg = fmaxf(mg, lds_m[ww][q]);
    float lg = 0.f, og = 0.f;
    #pragma unroll
    for (int ww = 0; ww < AW; ++ww) {
      float sc = __builtin_amdgcn_exp2f(lds_m[ww][q] - mg);
      lg += lds_l[ww][q] * sc;
      og += lds_o[ww][q][d] * sc;
    }
    int qq = q0 + q;
    if (qq < QQ)
      aout[((size_t)b * QQ + qq) * DIMN + m * DHD + d] = og / lg;
  }
}

// ---------- K7: tiled epilogue: 16 q / block, 256 threads ----------
#define EQ 16
#define EPAD 4
__global__ __launch_bounds__(256)
void k_epi2(const float* __restrict__ a, const float* __restrict__ x,
            const float* __restrict__ Wproj, const float* __restrict__ bproj,
            const float* __restrict__ preg, const float* __restrict__ preb,
            const float* __restrict__ W1, const float* __restrict__ b1,
            const float* __restrict__ W2, const float* __restrict__ b2,
            const float* __restrict__ postg, const float* __restrict__ postb,
            float* __restrict__ out) {
  __shared__ float sa[EQ][DIMN + EPAD];
  __shared__ float sx[EQ][DIMN + EPAD];
  __shared__ float sln[EQ][DIMN + EPAD];
  __shared__ float sh[EQ][2 * DIMN];
  __shared__ float stats[EQ][2];
  int q0 = blockIdx.x * EQ;
  int b  = blockIdx.y;
  int t  = threadIdx.x;
  int d  = t & 127, rg = t >> 7;

  #pragma unroll
  for (int i = 0; i < 8; ++i) {
    int e = i * 256 + t;
    int q = e >> 7, dd = e & 127;
    int qq = q0 + q;
    sa[q][dd] = (qq < QQ) ? a[((size_t)b * QQ + qq) * DIMN + dd] : 0.f;
  }
  #pragma unroll
  for (int i = 0; i < 8; ++i) {
    int e = i * 256 + t;
    int dd = e >> 4, qi = e & 15;
    int qq = q0 + qi;
    sx[qi][dd] = (qq < QQ) ? x[((size_t)b * DIMN + dd) * QQ + qq] : 0.f;
  }
  __syncthreads();

  float z[8];
  {
    const float4* Wp = (const float4*)Wproj + d * 32;
    float bp = bproj[d];
    #pragma unroll
    for (int r = 0; r < 8; ++r) z[r] = bp + sx[rg * 8 + r][d];
    for (int c4 = 0; c4 < 32; ++c4) {
      float4 w = Wp[c4];
      #pragma unroll
      for (int r = 0; r < 8; ++r) {
        float4 av = *(const float4*)&sa[rg * 8 + r][c4 * 4];
        z[r] += w.x * av.x + w.y * av.y + w.z * av.z + w.w * av.w;
      }
    }
  }
  __syncthreads();
  #pragma unroll
  for (int r = 0; r < 8; ++r) sx[rg * 8 + r][d] = z[r];
  __syncthreads();
  {
    int rt = t >> 4, lane = t & 15;
    float s = 0.f, s2 = 0.f;
    #pragma unroll
    for (int j = 0; j < 8; ++j) { float v = sx[rt][lane + 16 * j]; s += v; s2 += v * v; }
    #pragma unroll
    for (int msk = 1; msk < 16; msk <<= 1) { s += __shfl_xor(s, msk, 16); s2 += __shfl_xor(s2, msk, 16); }
    if (lane == 0) { stats[rt][0] = s * (1.f / 128.f); stats[rt][1] = s2 * (1.f / 128.f); }
  }
  __syncthreads();
  float ln1[8];
  {
    float pg = preg[d], pb = preb[d];
    #pragma unroll
    for (int r = 0; r < 8; ++r) {
      int rr = rg * 8 + r;
      float mu  = stats[rr][0];
      float var = fmaxf(stats[rr][1] - mu * mu, 0.f);
      ln1[r] = (z[r] - mu) * rsqrtf(var + 1e-5f) * pg + pb;
      sln[rr][d] = ln1[r];
    }
  }
  __syncthreads();
  {
    const float4* W1p = (const float4*)W1 + t * 32;
    float hb = b1[t];
    float h[16];
    #pragma unroll
    for (int r = 0; r < 16; ++r) h[r] = hb;
    for (int c4 = 0; c4 < 32; ++c4) {
      float4 w = W1p[c4];
      #pragma unroll
      for (int r = 0; r < 16; ++r) {
        float4 lv = *(const float4*)&sln[r][c4 * 4];
        h[r] += w.x * lv.x + w.y * lv.y + w.z * lv.z + w.w * lv.w;
      }
    }
    #pragma unroll
    for (int r = 0; r < 16; ++r) {
      float hv = h[r];
      sh[r][t] = 0.5f * hv * (1.f + erff(hv * 0.70710678118f));
    }
  }
  __syncthreads();
  float o[8];
  {
    const float4* W2p = (const float4*)W2 + d * 64;
    float b2v = b2[d];
    #pragma unroll
    for (int r = 0; r < 8; ++r) o[r] = ln1[r] + b2v;
    for (int c4 = 0; c4 < 64; ++c4) {
      float4 w = W2p[c4];
      #pragma unroll
      for (int r = 0; r < 8; ++r) {
        float4 hv = *(const float4*)&sh[rg * 8 + r][c4 * 4];
        o[r] += w.x * hv.x + w.y * hv.y + w.z * hv.z + w.w * hv.w;
      }
    }
  }
  __syncthreads();
  #pragma unroll
  for (int r = 0; r < 8; ++r) sx[rg * 8 + r][d] = o[r];
  __syncthreads();
  {
    int rt = t >> 4, lane = t & 15;
    float s = 0.f, s2 = 0.f;
    #pragma unroll
    for (int j = 0; j < 8; ++j) { float v = sx[rt][lane + 16 * j]; s += v; s2 += v * v; }
    #pragma unroll
    for (int msk = 1; msk < 16; msk <<= 1) { s += __shfl_xor(s, msk, 16); s2 += __shfl_xor(s2, msk, 16); }
    if (lane == 0) { stats[rt][0] = s * (1.f / 128.f); stats[rt][1] = s2 * (1.f / 128.f); }
  }
  __syncthreads();
  {
    float pg = postg[d], pb = postb[d];
    #pragma unroll
    for (int r = 0; r < 8; ++r) {
      int rr = rg * 8 + r;
      float mu  = stats[rr][0];
      float var = fmaxf(stats[rr][1] - mu * mu, 0.f);
      sa[rr][d] = (o[r] - mu) * rsqrtf(var + 1e-5f) * pg + pb;
    }
  }
  __syncthreads();
  #pragma unroll
  for (int i = 0; i < 8; ++i) {
    int e = i * 256 + t;
    int dd = e >> 4, qi = e & 15;
    int qq = q0 + qi;
    if (qq < QQ) out[((size_t)b * DIMN + dd) * QQ + qq] = sa[qi][dd];
  }
}

// ---------- launch ----------
extern "C" void kernel_launch(void* const* d_in, const int* in_sizes, int n_in,
                              void* d_out, int out_size, void* d_ws, size_t ws_size,
                              hipStream_t stream) {
  const float* x        = (const float*)d_in[0];
  const float* feature  = (const float*)d_in[1];
  const float* I_inv    = (const float*)d_in[2];
  const float* E_inv    = (const float*)d_in[3];
  const float* bev_grid = (const float*)d_in[4];
  const float* plane    = (const float*)d_in[5];
  const float* W_cam    = (const float*)d_in[6];
  const float* W_img    = (const float*)d_in[7];
  const float* W_bev    = (const float*)d_in[8];
  const float* b_bev    = (const float*)d_in[9];
  const float* fp_g = (const float*)d_in[10];
  const float* fp_b = (const float*)d_in[11];
  const float* fp_m = (const float*)d_in[12];
  const float* fp_v = (const float*)d_in[13];
  const float* fl_g = (const float*)d_in[14];
  const float* fl_b = (const float*)d_in[15];
  const float* fl_m = (const float*)d_in[16];
  const float* fl_v = (const float*)d_in[17];
  const float* W_fproj = (const float*)d_in[18];
  const float* W_flin  = (const float*)d_in[19];
  const float* q_ln_g = (const float*)d_in[20];
  const float* q_ln_b = (const float*)d_in[21];
  const float* Wq = (const float*)d_in[22];
  const float* bq = (const float*)d_in[23];
  const float* k_ln_g = (const float*)d_in[24];
  const float* k_ln_b = (const float*)d_in[25];
  const float* Wk = (const float*)d_in[26];
  const float* bk = (const float*)d_in[27];
  const float* v_ln_g = (const float*)d_in[28];
  const float* v_ln_b = (const float*)d_in[29];
  const float* Wv = (const float*)d_in[30];
  const float* bv = (const float*)d_in[31];
  const float* Wproj = (const float*)d_in[32];
  const float* bproj = (const float*)d_in[33];
  const float* pre_g = (const float*)d_in[34];
  const float* pre_b = (const float*)d_in[35];
  const float* W1 = (const float*)d_in[36];
  const float* b1 = (const float*)d_in[37];
  const float* W2 = (const float*)d_in[38];
  const float* b2 = (const float*)d_in[39];
  const float* post_g = (const float*)d_in[40];
  const float* post_b = (const float*)d_in[41];

  float* ws    = (float*)d_ws;
  float* ce    = ws;                       // 2048
  float* keyb  = ce + 2048;                // 2,580,480
  float* valb  = keyb + 2580480;           // 2,580,480
  float* query = valb + 2580480;           // 3,840,000
  float* aout  = query + 3840000;          // 640,000
  unsigned short* qhB = (unsigned short*)(aout + 640000);  // 3,840,000 u16
  unsigned short* vhB = qhB + 3840000;                     // 2,580,480 u16 (tail OOB spills into khB: safe)
  unsigned short* khB = vhB + 2580480;                     // 2,580,480 u16
  unsigned short* WfpB = khB + 2580480;                    // 32768
  unsigned short* WflB = WfpB + 32768;                     // 32768
  unsigned short* WqB  = WflB + 32768;                     // 16384
  unsigned short* WkB  = WqB + 16384;                      // 16384
  unsigned short* WvB  = WkB + 16384;                      // 16384

  k_cvtw<<<112, 256, 0, stream>>>(W_fproj, W_flin, Wq, Wk, Wv,
                                  WfpB, WflB, WqB, WkB, WvB);
  k_cembed<<<12, 128, 0, stream>>>(W_cam, E_inv, ce);
  k_img<<<dim3(KK, 12), 128, 0, stream>>>(I_inv, E_inv, plane, W_img, ce, keyb);
  k_query<<<dim3(QQ, 12), 128, 0, stream>>>(bev_grid, W_bev, b_bev, ce, x, query);
  k_featconv_mfma<<<dim3((KK + FTP - 1) / FTP, 12), 256, 0, stream>>>(feature,
      fp_g, fp_b, fp_m, fp_v, fl_g, fl_b, fl_m, fl_v, WfpB, WflB, keyb, valb);
  k_lnproj_mfma<0><<<dim3((QQ + 63) / 64, 12), 256, 0, stream>>>(query, QQ,
      q_ln_g, q_ln_b, WqB, bq, QSCALE, qhB);
  k_lnproj_mfma<0><<<dim3((KK + 63) / 64, 12), 256, 0, stream>>>(keyb, KK,
      k_ln_g, k_ln_b, WkB, bk, 1.0f, khB);
  k_lnproj_mfma<1><<<dim3((KK + 63) / 64, 12), 256, 0, stream>>>(valb, KK,
      v_ln_g, v_ln_b, WvB, bv, 1.0f, vhB);
  k_attn_mfma<<<dim3((QQ + 15) / 16, NHEAD, NB), 512, 0, stream>>>(qhB, khB, vhB, aout);
  k_epi2<<<dim3((QQ + EQ - 1) / EQ, NB), 256, 0, stream>>>(aout, x, Wproj, bproj,
      pre_g, pre_b, W1, b1, W2, b2, post_g, post_b, (float*)d_out);
}

// Round 10
// 484.147 us; speedup vs baseline: 1.5308x; 1.0270x over previous
//
#include <hip/hip_runtime.h>

#define NB    2
#define NCAM  6
#define FD    256
#define KK    1680
#define DIMN  128
#define NHEAD 4
#define DHD   32
#define QQ    2500
#define SCALE 0.17677669529663687f
// SCALE * log2(e): scores computed directly in log2 domain
#define QSCALE ((float)(0.17677669529663687 * 1.4426950408889634))

typedef short bf8 __attribute__((ext_vector_type(8)));
typedef float f4  __attribute__((ext_vector_type(4)));

__device__ __forceinline__ unsigned short f2bf(float f) {
  unsigned int u = __float_as_uint(f);
  unsigned int r = (u + 0x7fffu + ((u >> 16) & 1u)) >> 16;
  return (unsigned short)r;
}
// truncating bf16 (1 VALU op) — used only for softmax P in [0, 256]
__device__ __forceinline__ unsigned short f2bf_rz(float f) {
  return (unsigned short)(__float_as_uint(f) >> 16);
}

// ---------- helpers ----------
__device__ __forceinline__ float blk_sum128(float v, float* red) {
  #pragma unroll
  for (int o = 32; o > 0; o >>= 1) v += __shfl_down(v, o);
  int t = threadIdx.x;
  if ((t & 63) == 0) red[t >> 6] = v;
  __syncthreads();
  float r = red[0] + red[1];
  __syncthreads();
  return r;
}

// ---------- K0: weight bf16 conversion + camera-center embedding (fused) ----------
__global__ __launch_bounds__(256)
void k_cvtw(const float* __restrict__ a0, const float* __restrict__ a1,
            const float* __restrict__ a2, const float* __restrict__ a3,
            const float* __restrict__ a4,
            unsigned short* __restrict__ b0, unsigned short* __restrict__ b1,
            unsigned short* __restrict__ b2, unsigned short* __restrict__ b3,
            unsigned short* __restrict__ b4,
            const float* __restrict__ W_cam, const float* __restrict__ E_inv,
            float* __restrict__ ce) {
  int bid = blockIdx.x;
  int t = threadIdx.x;
  if (bid >= 112) {   // 6 blocks: cembed, bn = (bid-112)*2 + (t>>7)
    int bn = (bid - 112) * 2 + (t >> 7);
    int d  = t & 127;
    const float* e = E_inv + bn * 16;
    float s = 0.f;
    #pragma unroll
    for (int c = 0; c < 4; ++c) s += W_cam[d * 4 + c] * e[c * 4 + 3];
    ce[bn * 128 + d] = s;
    return;
  }
  const float* s; unsigned short* d; int off;
  if (bid < 32)      { s = a0; d = b0; off = bid; }
  else if (bid < 64) { s = a1; d = b1; off = bid - 32; }
  else if (bid < 80) { s = a2; d = b2; off = bid - 64; }
  else if (bid < 96) { s = a3; d = b3; off = bid - 80; }
  else               { s = a4; d = b4; off = bid - 96; }
  int i = off * 1024 + t * 4;
  float4 v = *(const float4*)&s[i];
  uint2 pk = make_uint2((unsigned)f2bf(v.x) | ((unsigned)f2bf(v.y) << 16),
                        (unsigned)f2bf(v.z) | ((unsigned)f2bf(v.w) << 16));
  *(uint2*)&d[i] = pk;
}

// ---------- K2: per-pixel ray embedding; one wave per pixel, shuffle-only norm ----------
__global__ __launch_bounds__(256)
void k_img(const float* __restrict__ I_inv, const float* __restrict__ E_inv,
           const float* __restrict__ plane, const float* __restrict__ W_img,
           const float* __restrict__ ce, float* __restrict__ key) {
  int w = threadIdx.x >> 6, lane = threadIdx.x & 63;
  int p  = blockIdx.x * 4 + w;     // KK = 1680 = 420*4
  int bn = blockIdx.y;
  const float* Ii = I_inv + bn * 9;
  const float* Ei = E_inv + bn * 16;
  float pl0 = plane[p], pl1 = plane[KK + p], pl2 = plane[2 * KK + p];
  float c0 = Ii[0]*pl0 + Ii[1]*pl1 + Ii[2]*pl2;
  float c1 = Ii[3]*pl0 + Ii[4]*pl1 + Ii[5]*pl2;
  float c2 = Ii[6]*pl0 + Ii[7]*pl1 + Ii[8]*pl2;
  float d0 = Ei[0]*c0 + Ei[1]*c1 + Ei[2]*c2  + Ei[3];
  float d1 = Ei[4]*c0 + Ei[5]*c1 + Ei[6]*c2  + Ei[7];
  float d2 = Ei[8]*c0 + Ei[9]*c1 + Ei[10]*c2 + Ei[11];
  float d3 = Ei[12]*c0 + Ei[13]*c1 + Ei[14]*c2 + Ei[15];
  int da = lane, db = lane + 64;
  float4 wa = *(const float4*)&W_img[da * 4];
  float4 wb = *(const float4*)&W_img[db * 4];
  float v0 = wa.x*d0 + wa.y*d1 + wa.z*d2 + wa.w*d3 - ce[bn * 128 + da];
  float v1 = wb.x*d0 + wb.y*d1 + wb.z*d2 + wb.w*d3 - ce[bn * 128 + db];
  float ss = v0 * v0 + v1 * v1;
  #pragma unroll
  for (int o = 32; o > 0; o >>= 1) ss += __shfl_xor(ss, o);
  float inv = 1.f / (sqrtf(ss) + 1e-7f);
  size_t base = ((size_t)bn * KK + p) * DIMN;
  key[base + da] = v0 * inv;
  key[base + db] = v1 * inv;
}

// ---------- K3: BEV positional embedding + x; one wave per query pixel ----------
__global__ __launch_bounds__(256)
void k_query(const float* __restrict__ bev_grid, const float* __restrict__ W_bev,
             const float* __restrict__ b_bev, const float* __restrict__ ce,
             const float* __restrict__ x, float* __restrict__ query) {
  int w = threadIdx.x >> 6, lane = threadIdx.x & 63;
  int q  = blockIdx.x * 4 + w;     // QQ = 2500 = 625*4
  int bn = blockIdx.y;
  int b  = bn / NCAM;
  float g0 = bev_grid[q], g1 = bev_grid[QQ + q];
  int da = lane, db = lane + 64;
  float v0 = W_bev[da*2] * g0 + W_bev[da*2+1] * g1 + b_bev[da] - ce[bn * 128 + da];
  float v1 = W_bev[db*2] * g0 + W_bev[db*2+1] * g1 + b_bev[db] - ce[bn * 128 + db];
  float ss = v0 * v0 + v1 * v1;
  #pragma unroll
  for (int o = 32; o > 0; o >>= 1) ss += __shfl_xor(ss, o);
  float inv = 1.f / (sqrtf(ss) + 1e-7f);
  size_t base = ((size_t)bn * QQ + q) * DIMN;
  query[base + da] = v0 * inv + x[(size_t)(b * DIMN + da) * QQ + q];
  query[base + db] = v1 * inv + x[(size_t)(b * DIMN + db) * QQ + q];
}

// ---------- K4: BN+ReLU + dual 1x1 conv via MFMA; key += fproj, val = flin ----------
#define FTP 64
#define FSTR 264   // u16 row stride: 16B-aligned, 132 dwords (bank stride 4)
__global__ __launch_bounds__(256)
void k_featconv_mfma(const float* __restrict__ feat,
                     const float* __restrict__ g1c, const float* __restrict__ b1c,
                     const float* __restrict__ m1c, const float* __restrict__ v1c,
                     const float* __restrict__ g2c, const float* __restrict__ b2c,
                     const float* __restrict__ m2c, const float* __restrict__ v2c,
                     const unsigned short* __restrict__ WfpB,
                     const unsigned short* __restrict__ WflB,
                     float* __restrict__ key, float* __restrict__ val) {
  __shared__ unsigned short act[FTP * FSTR];
  __shared__ float scs[2][FD], shs[2][FD];
  int tile = blockIdx.x, bn = blockIdx.y;
  int p0 = tile * FTP;
  int t = threadIdx.x;
  {
    float s1 = g1c[t] * rsqrtf(v1c[t] + 1e-5f);
    scs[0][t] = s1; shs[0][t] = b1c[t] - m1c[t] * s1;
    float s2 = g2c[t] * rsqrtf(v2c[t] + 1e-5f);
    scs[1][t] = s2; shs[1][t] = b2c[t] - m2c[t] * s2;
  }
  int w = t >> 6, l = t & 63, c = l & 15, g = l >> 4;
  const float* fb = feat + (size_t)bn * FD * KK;
  for (int var = 0; var < 2; ++var) {
    __syncthreads();
    #pragma unroll
    for (int it = 0; it < 16; ++it) {
      int e   = it * 256 + t;
      int cin = e >> 4;
      int pq  = (e & 15) * 4;
      int pp  = min(p0 + pq, KK - 4);
      float4 r = *(const float4*)&fb[(size_t)cin * KK + pp];
      float s = scs[var][cin], h = shs[var][cin];
      act[(pq + 0) * FSTR + cin] = f2bf(fmaxf(r.x * s + h, 0.f));
      act[(pq + 1) * FSTR + cin] = f2bf(fmaxf(r.y * s + h, 0.f));
      act[(pq + 2) * FSTR + cin] = f2bf(fmaxf(r.z * s + h, 0.f));
      act[(pq + 3) * FSTR + cin] = f2bf(fmaxf(r.w * s + h, 0.f));
    }
    __syncthreads();
    const unsigned short* W = var ? WflB : WfpB;
    bf8 af[8];
    #pragma unroll
    for (int kk = 0; kk < 8; ++kk)
      af[kk] = *(const bf8*)&act[(w * 16 + c) * FSTR + kk * 32 + g * 8];
    f4 acc[8];
    #pragma unroll
    for (int grp = 0; grp < 8; ++grp) {
      f4 a = {0.f, 0.f, 0.f, 0.f};
      #pragma unroll
      for (int kk = 0; kk < 8; ++kk) {
        bf8 bfr = *(const bf8*)&W[(grp * 16 + c) * FD + kk * 32 + g * 8];
        a = __builtin_amdgcn_mfma_f32_16x16x32_bf16(af[kk], bfr, a, 0, 0, 0);
      }
      acc[grp] = a;
    }
    #pragma unroll
    for (int i = 0; i < 4; ++i) {
      int pos = p0 + w * 16 + 4 * g + i;
      if (pos < KK) {
        size_t base = ((size_t)bn * KK + pos) * DIMN + c;
        if (var == 0) {
          #pragma unroll
          for (int grp = 0; grp < 8; ++grp) key[base + grp * 16] += acc[grp][i];
        } else {
          #pragma unroll
          for (int grp = 0; grp < 8; ++grp) val[base + grp * 16] = acc[grp][i];
        }
      }
    }
  }
}

// ---------- K5: LayerNorm (f32) + 128x128 projection via MFMA -> bf16 ----------
#define LSTR 136   // u16 row stride: 16B-aligned, 68 dwords (bank stride 4)
template<int MODE>
__global__ __launch_bounds__(256)
void k_lnproj_mfma(const float* __restrict__ in, int nrows,
                   const float* __restrict__ lng, const float* __restrict__ lnbb,
                   const unsigned short* __restrict__ WB, const float* __restrict__ bias,
                   float scale, unsigned short* __restrict__ out) {
  __shared__ unsigned short lnb[64 * LSTR];
  int tile = blockIdx.x, bn = blockIdx.y;
  int t = threadIdx.x;
  int r0loc = tile * 64;
  int valid = nrows - r0loc; if (valid > 64) valid = 64;
  size_t gr0 = (size_t)bn * nrows + r0loc;
  int tk = t >> 2, qr = t & 3;
  int tkc = (tk < valid) ? tk : (valid - 1);
  const float* ip = &in[(gr0 + tkc) * DIMN + qr * 32];
  float xv[32];
  #pragma unroll
  for (int j = 0; j < 8; ++j) {
    float4 v = *(const float4*)&ip[j * 4];
    xv[j*4] = v.x; xv[j*4+1] = v.y; xv[j*4+2] = v.z; xv[j*4+3] = v.w;
  }
  float s = 0.f, s2 = 0.f;
  #pragma unroll
  for (int j = 0; j < 32; ++j) { s += xv[j]; s2 += xv[j] * xv[j]; }
  s  += __shfl_xor(s, 1, 4);  s  += __shfl_xor(s, 2, 4);
  s2 += __shfl_xor(s2, 1, 4); s2 += __shfl_xor(s2, 2, 4);
  float mu  = s * (1.f / 128.f);
  float var = fmaxf(s2 * (1.f / 128.f) - mu * mu, 0.f);
  float rin = rsqrtf(var + 1e-5f);
  #pragma unroll
  for (int j4 = 0; j4 < 8; ++j4) {
    int d = qr * 32 + j4 * 4;
    float4 gv = *(const float4*)&lng[d];
    float4 bv = *(const float4*)&lnbb[d];
    float l0 = (xv[j4*4+0] - mu) * rin * gv.x + bv.x;
    float l1 = (xv[j4*4+1] - mu) * rin * gv.y + bv.y;
    float l2 = (xv[j4*4+2] - mu) * rin * gv.z + bv.z;
    float l3 = (xv[j4*4+3] - mu) * rin * gv.w + bv.w;
    uint2 pk = make_uint2((unsigned)f2bf(l0) | ((unsigned)f2bf(l1) << 16),
                          (unsigned)f2bf(l2) | ((unsigned)f2bf(l3) << 16));
    *(uint2*)&lnb[tk * LSTR + d] = pk;
  }
  __syncthreads();
  int w = t >> 6, l = t & 63, c = l & 15, g = l >> 4;
  bf8 af[4];
  #pragma unroll
  for (int kk = 0; kk < 4; ++kk)
    af[kk] = *(const bf8*)&lnb[(w * 16 + c) * LSTR + kk * 32 + g * 8];
  f4 acc[8];
  #pragma unroll
  for (int grp = 0; grp < 8; ++grp) {
    f4 a = {0.f, 0.f, 0.f, 0.f};
    #pragma unroll
    for (int kk = 0; kk < 4; ++kk) {
      bf8 bfr = *(const bf8*)&WB[(grp * 16 + c) * DIMN + kk * 32 + g * 8];
      a = __builtin_amdgcn_mfma_f32_16x16x32_bf16(af[kk], bfr, a, 0, 0, 0);
    }
    acc[grp] = a;
  }
  if (MODE == 0) {
    #pragma unroll
    for (int grp = 0; grp < 8; ++grp) {
      float bv = bias[grp * 16 + c];
      #pragma unroll
      for (int i = 0; i < 4; ++i) {
        int rr = w * 16 + 4 * g + i;
        if (rr < valid)
          out[(gr0 + rr) * DIMN + grp * 16 + c] = f2bf((acc[grp][i] + bv) * scale);
      }
    }
  } else {
    #pragma unroll
    for (int grp = 0; grp < 8; ++grp) {
      float bv = bias[grp * 16 + c];
      #pragma unroll
      for (int i = 0; i < 4; ++i)
        lnb[(w * 16 + 4 * g + i) * LSTR + grp * 16 + c] = f2bf(acc[grp][i] + bv);
    }
    __syncthreads();
    #pragma unroll
    for (int it = 0; it < 32; ++it) {
      int e = it * 256 + t;
      int dout = e >> 6, tok = e & 63;
      if (tok < valid)
        out[((size_t)(bn * 4 + (dout >> 5)) * 32 + (dout & 31)) * KK + r0loc + tok]
            = lnb[tok * LSTR + dout];
    }
  }
}

// ---------- K6: MFMA flash attention, 8-way split-K, online softmax with defer-max ----------
#define AW 8
#define NCHUNK 53   // ceil(1680/32); chunk 52 has 16 keys
#define THR 8.0f    // log2 domain: p bounded by 2^8
__global__ __launch_bounds__(512)
void k_attn_mfma(const unsigned short* __restrict__ qhB, const unsigned short* __restrict__ khB,
                 const unsigned short* __restrict__ vhB, float* __restrict__ aout) {
  __shared__ unsigned short pls[AW][16 * 40];   // per-wave P transpose buffer
  __shared__ float lds_o[AW][16][32];           // unnormalized o partials
  __shared__ float lds_m[AW][16], lds_l[AW][16];
  int qt = blockIdx.x, m = blockIdx.y, b = blockIdx.z;
  int t = threadIdx.x;
  int w = t >> 6, l = t & 63;
  int c = l & 15, g = l >> 4;
  int q0 = qt * 16;

  bf8 qf[NCAM];
  #pragma unroll
  for (int n = 0; n < NCAM; ++n) {
    int q = q0 + c;
    if (q < QQ)
      qf[n] = *(const bf8*)&qhB[((size_t)(b * NCAM + n) * QQ + q) * DIMN + m * DHD + g * 8];
    else
      qf[n] = (bf8)0;
  }
  const f4 z4 = {0.f, 0.f, 0.f, 0.f};
  f4 o0 = z4, o1 = z4;
  float mrun[4], lp[4];
  #pragma unroll
  for (int i = 0; i < 4; ++i) { mrun[i] = -1e30f; lp[i] = 0.f; }

  for (int n = 0; n < NCAM; ++n) {
    const unsigned short* kb = khB + (size_t)(b * NCAM + n) * KK * DIMN + m * DHD;
    const unsigned short* vb = vhB + (size_t)((b * NCAM + n) * NHEAD + m) * DHD * KK;
    bf8 qa = qf[n];
    for (int j = w; j < NCHUNK; j += AW) {
      int k0 = j * 32;
      bool tail = (j == NCHUNK - 1);
      bf8 kf0 = *(const bf8*)&kb[(size_t)(k0 + c) * DIMN + g * 8];
      bf8 vf0 = *(const bf8*)&vb[(size_t)c * KK + k0 + g * 8];
      bf8 vf1 = *(const bf8*)&vb[(size_t)(16 + c) * KK + k0 + g * 8];
      f4 s0 = __builtin_amdgcn_mfma_f32_16x16x32_bf16(qa, kf0, z4, 0, 0, 0);
      f4 s1;
      if (!tail) {
        bf8 kf1 = *(const bf8*)&kb[(size_t)(k0 + 16 + c) * DIMN + g * 8];
        s1 = __builtin_amdgcn_mfma_f32_16x16x32_bf16(qa, kf1, z4, 0, 0, 0);
      } else {
        s1 = (f4){-1e30f, -1e30f, -1e30f, -1e30f};
      }
      float lm[4];
      #pragma unroll
      for (int i = 0; i < 4; ++i) lm[i] = fmaxf(s0[i], s1[i]);
      bool ok = (lm[0] <= mrun[0] + THR) && (lm[1] <= mrun[1] + THR)
             && (lm[2] <= mrun[2] + THR) && (lm[3] <= mrun[3] + THR);
      if (!__all(ok)) {
        #pragma unroll
        for (int i = 0; i < 4; ++i) {
          float tm = lm[i];
          #pragma unroll
          for (int msk = 1; msk < 16; msk <<= 1) tm = fmaxf(tm, __shfl_xor(tm, msk, 16));
          float mn = fmaxf(mrun[i], tm);
          float al = __builtin_amdgcn_exp2f(mrun[i] - mn);
          mrun[i] = mn;
          lp[i] *= al;
          o0[i] *= al; o1[i] *= al;
        }
      }
      #pragma unroll
      for (int i = 0; i < 4; ++i) {
        float p0 = __builtin_amdgcn_exp2f(s0[i] - mrun[i]);
        float p1 = __builtin_amdgcn_exp2f(s1[i] - mrun[i]);   // tail: exp2(-inf) = 0
        lp[i] += p0 + p1;
        pls[w][(4 * g + i) * 40 + c]      = f2bf_rz(p0);
        pls[w][(4 * g + i) * 40 + 16 + c] = f2bf_rz(p1);
      }
      bf8 pa = *(const bf8*)&pls[w][c * 40 + g * 8];
      o0 = __builtin_amdgcn_mfma_f32_16x16x32_bf16(pa, vf0, o0, 0, 0, 0);
      o1 = __builtin_amdgcn_mfma_f32_16x16x32_bf16(pa, vf1, o1, 0, 0, 0);
    }
  }
  #pragma unroll
  for (int i = 0; i < 4; ++i) {
    #pragma unroll
    for (int msk = 1; msk < 16; msk <<= 1) lp[i] += __shfl_xor(lp[i], msk, 16);
  }
  #pragma unroll
  for (int i = 0; i < 4; ++i) {
    int qr = 4 * g + i;
    if (c == 0) { lds_m[w][qr] = mrun[i]; lds_l[w][qr] = lp[i]; }
    lds_o[w][qr][c]      = o0[i];
    lds_o[w][qr][16 + c] = o1[i];
  }
  __syncthreads();
  {
    int q = t >> 5, d = t & 31;
    float mg = -1e30f;
    #pragma unroll
    for (int ww = 0; ww < AW; ++ww) mg = fmaxf(mg, lds_m[ww][q]);
    float lg = 0.f, og = 0.f;
    #pragma unroll
    for (int ww = 0; ww < AW; ++ww) {
      float sc = __builtin_amdgcn_exp2f(lds_m[ww][q] - mg);
      lg += lds_l[ww][q] * sc;
      og += lds_o[ww][q][d] * sc;
    }
    int qq = q0 + q;
    if (qq < QQ)
      aout[((size_t)b * QQ + qq) * DIMN + m * DHD + d] = og / lg;
  }
}

// ---------- K7: tiled epilogue: 16 q / block, 256 threads ----------
#define EQ 16
#define EPAD 4
__global__ __launch_bounds__(256)
void k_epi2(const float* __restrict__ a, const float* __restrict__ x,
            const float* __restrict__ Wproj, const float* __restrict__ bproj,
            const float* __restrict__ preg, const float* __restrict__ preb,
            const float* __restrict__ W1, const float* __restrict__ b1,
            const float* __restrict__ W2, const float* __restrict__ b2,
            const float* __restrict__ postg, const float* __restrict__ postb,
            float* __restrict__ out) {
  __shared__ float sa[EQ][DIMN + EPAD];
  __shared__ float sx[EQ][DIMN + EPAD];
  __shared__ float sln[EQ][DIMN + EPAD];
  __shared__ float sh[EQ][2 * DIMN];
  __shared__ float stats[EQ][2];
  int q0 = blockIdx.x * EQ;
  int b  = blockIdx.y;
  int t  = threadIdx.x;
  int d  = t & 127, rg = t >> 7;

  #pragma unroll
  for (int i = 0; i < 8; ++i) {
    int e = i * 256 + t;
    int q = e >> 7, dd = e & 127;
    int qq = q0 + q;
    sa[q][dd] = (qq < QQ) ? a[((size_t)b * QQ + qq) * DIMN + dd] : 0.f;
  }
  #pragma unroll
  for (int i = 0; i < 8; ++i) {
    int e = i * 256 + t;
    int dd = e >> 4, qi = e & 15;
    int qq = q0 + qi;
    sx[qi][dd] = (qq < QQ) ? x[((size_t)b * DIMN + dd) * QQ + qq] : 0.f;
  }
  __syncthreads();

  float z[8];
  {
    const float4* Wp = (const float4*)Wproj + d * 32;
    float bp = bproj[d];
    #pragma unroll
    for (int r = 0; r < 8; ++r) z[r] = bp + sx[rg * 8 + r][d];
    for (int c4 = 0; c4 < 32; ++c4) {
      float4 w = Wp[c4];
      #pragma unroll
      for (int r = 0; r < 8; ++r) {
        float4 av = *(const float4*)&sa[rg * 8 + r][c4 * 4];
        z[r] += w.x * av.x + w.y * av.y + w.z * av.z + w.w * av.w;
      }
    }
  }
  __syncthreads();
  #pragma unroll
  for (int r = 0; r < 8; ++r) sx[rg * 8 + r][d] = z[r];
  __syncthreads();
  {
    int rt = t >> 4, lane = t & 15;
    float s = 0.f, s2 = 0.f;
    #pragma unroll
    for (int j = 0; j < 8; ++j) { float v = sx[rt][lane + 16 * j]; s += v; s2 += v * v; }
    #pragma unroll
    for (int msk = 1; msk < 16; msk <<= 1) { s += __shfl_xor(s, msk, 16); s2 += __shfl_xor(s2, msk, 16); }
    if (lane == 0) { stats[rt][0] = s * (1.f / 128.f); stats[rt][1] = s2 * (1.f / 128.f); }
  }
  __syncthreads();
  float ln1[8];
  {
    float pg = preg[d], pb = preb[d];
    #pragma unroll
    for (int r = 0; r < 8; ++r) {
      int rr = rg * 8 + r;
      float mu  = stats[rr][0];
      float var = fmaxf(stats[rr][1] - mu * mu, 0.f);
      ln1[r] = (z[r] - mu) * rsqrtf(var + 1e-5f) * pg + pb;
      sln[rr][d] = ln1[r];
    }
  }
  __syncthreads();
  {
    const float4* W1p = (const float4*)W1 + t * 32;
    float hb = b1[t];
    float h[16];
    #pragma unroll
    for (int r = 0; r < 16; ++r) h[r] = hb;
    for (int c4 = 0; c4 < 32; ++c4) {
      float4 w = W1p[c4];
      #pragma unroll
      for (int r = 0; r < 16; ++r) {
        float4 lv = *(const float4*)&sln[r][c4 * 4];
        h[r] += w.x * lv.x + w.y * lv.y + w.z * lv.z + w.w * lv.w;
      }
    }
    #pragma unroll
    for (int r = 0; r < 16; ++r) {
      float hv = h[r];
      sh[r][t] = 0.5f * hv * (1.f + erff(hv * 0.70710678118f));
    }
  }
  __syncthreads();
  float o[8];
  {
    const float4* W2p = (const float4*)W2 + d * 64;
    float b2v = b2[d];
    #pragma unroll
    for (int r = 0; r < 8; ++r) o[r] = ln1[r] + b2v;
    for (int c4 = 0; c4 < 64; ++c4) {
      float4 w = W2p[c4];
      #pragma unroll
      for (int r = 0; r < 8; ++r) {
        float4 hv = *(const float4*)&sh[rg * 8 + r][c4 * 4];
        o[r] += w.x * hv.x + w.y * hv.y + w.z * hv.z + w.w * hv.w;
      }
    }
  }
  __syncthreads();
  #pragma unroll
  for (int r = 0; r < 8; ++r) sx[rg * 8 + r][d] = o[r];
  __syncthreads();
  {
    int rt = t >> 4, lane = t & 15;
    float s = 0.f, s2 = 0.f;
    #pragma unroll
    for (int j = 0; j < 8; ++j) { float v = sx[rt][lane + 16 * j]; s += v; s2 += v * v; }
    #pragma unroll
    for (int msk = 1; msk < 16; msk <<= 1) { s += __shfl_xor(s, msk, 16); s2 += __shfl_xor(s2, msk, 16); }
    if (lane == 0) { stats[rt][0] = s * (1.f / 128.f); stats[rt][1] = s2 * (1.f / 128.f); }
  }
  __syncthreads();
  {
    float pg = postg[d], pb = postb[d];
    #pragma unroll
    for (int r = 0; r < 8; ++r) {
      int rr = rg * 8 + r;
      float mu  = stats[rr][0];
      float var = fmaxf(stats[rr][1] - mu * mu, 0.f);
      sa[rr][d] = (o[r] - mu) * rsqrtf(var + 1e-5f) * pg + pb;
    }
  }
  __syncthreads();
  #pragma unroll
  for (int i = 0; i < 8; ++i) {
    int e = i * 256 + t;
    int dd = e >> 4, qi = e & 15;
    int qq = q0 + qi;
    if (qq < QQ) out[((size_t)b * DIMN + dd) * QQ + qq] = sa[qi][dd];
  }
}

// ---------- launch ----------
extern "C" void kernel_launch(void* const* d_in, const int* in_sizes, int n_in,
                              void* d_out, int out_size, void* d_ws, size_t ws_size,
                              hipStream_t stream) {
  const float* x        = (const float*)d_in[0];
  const float* feature  = (const float*)d_in[1];
  const float* I_inv    = (const float*)d_in[2];
  const float* E_inv    = (const float*)d_in[3];
  const float* bev_grid = (const float*)d_in[4];
  const float* plane    = (const float*)d_in[5];
  const float* W_cam    = (const float*)d_in[6];
  const float* W_img    = (const float*)d_in[7];
  const float* W_bev    = (const float*)d_in[8];
  const float* b_bev    = (const float*)d_in[9];
  const float* fp_g = (const float*)d_in[10];
  const float* fp_b = (const float*)d_in[11];
  const float* fp_m = (const float*)d_in[12];
  const float* fp_v = (const float*)d_in[13];
  const float* fl_g = (const float*)d_in[14];
  const float* fl_b = (const float*)d_in[15];
  const float* fl_m = (const float*)d_in[16];
  const float* fl_v = (const float*)d_in[17];
  const float* W_fproj = (const float*)d_in[18];
  const float* W_flin  = (const float*)d_in[19];
  const float* q_ln_g = (const float*)d_in[20];
  const float* q_ln_b = (const float*)d_in[21];
  const float* Wq = (const float*)d_in[22];
  const float* bq = (const float*)d_in[23];
  const float* k_ln_g = (const float*)d_in[24];
  const float* k_ln_b = (const float*)d_in[25];
  const float* Wk = (const float*)d_in[26];
  const float* bk = (const float*)d_in[27];
  const float* v_ln_g = (const float*)d_in[28];
  const float* v_ln_b = (const float*)d_in[29];
  const float* Wv = (const float*)d_in[30];
  const float* bv = (const float*)d_in[31];
  const float* Wproj = (const float*)d_in[32];
  const float* bproj = (const float*)d_in[33];
  const float* pre_g = (const float*)d_in[34];
  const float* pre_b = (const float*)d_in[35];
  const float* W1 = (const float*)d_in[36];
  const float* b1 = (const float*)d_in[37];
  const float* W2 = (const float*)d_in[38];
  const float* b2 = (const float*)d_in[39];
  const float* post_g = (const float*)d_in[40];
  const float* post_b = (const float*)d_in[41];

  float* ws    = (float*)d_ws;
  float* ce    = ws;                       // 2048
  float* keyb  = ce + 2048;                // 2,580,480
  float* valb  = keyb + 2580480;           // 2,580,480
  float* query = valb + 2580480;           // 3,840,000
  float* aout  = query + 3840000;          // 640,000
  unsigned short* qhB = (unsigned short*)(aout + 640000);  // 3,840,000 u16
  unsigned short* vhB = qhB + 3840000;                     // 2,580,480 u16 (tail OOB spills into khB: safe)
  unsigned short* khB = vhB + 2580480;                     // 2,580,480 u16
  unsigned short* WfpB = khB + 2580480;                    // 32768
  unsigned short* WflB = WfpB + 32768;                     // 32768
  unsigned short* WqB  = WflB + 32768;                     // 16384
  unsigned short* WkB  = WqB + 16384;                      // 16384
  unsigned short* WvB  = WkB + 16384;                      // 16384

  k_cvtw<<<118, 256, 0, stream>>>(W_fproj, W_flin, Wq, Wk, Wv,
                                  WfpB, WflB, WqB, WkB, WvB, W_cam, E_inv, ce);
  k_img<<<dim3(KK / 4, 12), 256, 0, stream>>>(I_inv, E_inv, plane, W_img, ce, keyb);
  k_query<<<dim3(QQ / 4, 12), 256, 0, stream>>>(bev_grid, W_bev, b_bev, ce, x, query);
  k_featconv_mfma<<<dim3((KK + FTP - 1) / FTP, 12), 256, 0, stream>>>(feature,
      fp_g, fp_b, fp_m, fp_v, fl_g, fl_b, fl_m, fl_v, WfpB, WflB, keyb, valb);
  k_lnproj_mfma<0><<<dim3((QQ + 63) / 64, 12), 256, 0, stream>>>(query, QQ,
      q_ln_g, q_ln_b, WqB, bq, QSCALE, qhB);
  k_lnproj_mfma<0><<<dim3((KK + 63) / 64, 12), 256, 0, stream>>>(keyb, KK,
      k_ln_g, k_ln_b, WkB, bk, 1.0f, khB);
  k_lnproj_mfma<1><<<dim3((KK + 63) / 64, 12), 256, 0, stream>>>(valb, KK,
      v_ln_g, v_ln_b, WvB, bv, 1.0f, vhB);
  k_attn_mfma<<<dim3((QQ + 15) / 16, NHEAD, NB), 512, 0, stream>>>(qhB, khB, vhB, aout);
  k_epi2<<<dim3((QQ + EQ - 1) / EQ, NB), 256, 0, stream>>>(aout, x, Wproj, bproj,
      pre_g, pre_b, W1, b1, W2, b2, post_g, post_b, (float*)d_out);
}